// Round 1
// baseline (1571.173 us; speedup 1.0000x reference)
//
#include <hip/hip_runtime.h>
#include <math.h>

// Problem constants
#define Bb 2
#define Ll 2048
#define DMODEL 1024
#define DINNER 2048
#define DSTATE 8
#define DTRANK 64
#define DCONV 4
#define MM (Bb*Ll)          // 4096 rows
// scan chunking
#define NCH 64
#define CL 32               // NCH*CL == Ll

__device__ __forceinline__ float silu_f(float x) {
    return x / (1.0f + __expf(-x));
}
__device__ __forceinline__ float softplus_f(float x) {
    return fmaxf(x, 0.0f) + log1pf(__expf(-fabsf(x)));
}

// ---------------------------------------------------------------------------
// Tiled fp32 GEMM: C[M,N] = epi(A[M,K] @ B[K,N] + bias)
// 64x64 block, 256 threads, each thread 4x4, K-tile 16.
// EPI: 0 = none, 1 = silu(x + bias[n]), 2 = softplus(x + bias[n])
// ---------------------------------------------------------------------------
template <int EPI>
__global__ __launch_bounds__(256) void gemm_tiled(
    const float* __restrict__ A, const float* __restrict__ B,
    float* __restrict__ C, int M, int N, int K,
    int lda, int ldb, int ldc, const float* __restrict__ bias)
{
    __shared__ float As[16][68];  // [k][m], +4 pad keeps float4 alignment
    __shared__ float Bs[16][68];  // [k][n]

    const int bm = blockIdx.y * 64;
    const int bn = blockIdx.x * 64;
    const int tid = threadIdx.x;
    const int tx = tid & 15;      // col group
    const int ty = tid >> 4;      // row group

    float acc[4][4];
#pragma unroll
    for (int i = 0; i < 4; ++i)
#pragma unroll
        for (int j = 0; j < 4; ++j) acc[i][j] = 0.0f;

    const int ar = tid >> 2;            // 0..63 row in A tile
    const int ac = (tid & 3) << 2;      // 0,4,8,12 col in A tile
    const int br = tid >> 4;            // 0..15 row in B tile
    const int bc = (tid & 15) << 2;     // 0..60 col in B tile

    for (int k0 = 0; k0 < K; k0 += 16) {
        float4 av = make_float4(0.f, 0.f, 0.f, 0.f);
        if (bm + ar < M)
            av = *(const float4*)&A[(size_t)(bm + ar) * lda + k0 + ac];
        As[ac + 0][ar] = av.x;
        As[ac + 1][ar] = av.y;
        As[ac + 2][ar] = av.z;
        As[ac + 3][ar] = av.w;

        float4 bv = make_float4(0.f, 0.f, 0.f, 0.f);
        if (bn + bc < N)
            bv = *(const float4*)&B[(size_t)(k0 + br) * ldb + bn + bc];
        *(float4*)&Bs[br][bc] = bv;

        __syncthreads();

#pragma unroll
        for (int k = 0; k < 16; ++k) {
            float4 a4 = *(float4*)&As[k][ty * 4];
            float4 b4 = *(float4*)&Bs[k][tx * 4];
            float am[4] = {a4.x, a4.y, a4.z, a4.w};
            float bn4[4] = {b4.x, b4.y, b4.z, b4.w};
#pragma unroll
            for (int i = 0; i < 4; ++i)
#pragma unroll
                for (int j = 0; j < 4; ++j)
                    acc[i][j] = fmaf(am[i], bn4[j], acc[i][j]);
        }
        __syncthreads();
    }

    const int col = bn + tx * 4;
    if (col >= N) return;
#pragma unroll
    for (int i = 0; i < 4; ++i) {
        int row = bm + ty * 4 + i;
        if (row >= M) continue;
        float4 v = make_float4(acc[i][0], acc[i][1], acc[i][2], acc[i][3]);
        if (EPI == 1) {
            v.x = silu_f(v.x + bias[col + 0]);
            v.y = silu_f(v.y + bias[col + 1]);
            v.z = silu_f(v.z + bias[col + 2]);
            v.w = silu_f(v.w + bias[col + 3]);
        } else if (EPI == 2) {
            v.x = softplus_f(v.x + bias[col + 0]);
            v.y = softplus_f(v.y + bias[col + 1]);
            v.z = softplus_f(v.z + bias[col + 2]);
            v.w = softplus_f(v.w + bias[col + 3]);
        }
        *(float4*)&C[(size_t)row * ldc + col] = v;
    }
}

// ---------------------------------------------------------------------------
// Depthwise causal conv, k=4: xc_pre[b,l,d] = sum_k x_in[b,l+k-3,d]*dwk[k,d]
// x_in = xz[..., 0:2048] (row stride 4096)
// ---------------------------------------------------------------------------
__global__ __launch_bounds__(256) void dwconv_kernel(
    const float* __restrict__ xz, const float* __restrict__ dwk,
    float* __restrict__ xc_pre)
{
    size_t i = (size_t)blockIdx.x * 256 + threadIdx.x;
    if (i >= (size_t)MM * DINNER) return;
    int d = (int)(i & (DINNER - 1));
    size_t bl = i >> 11;               // b*2048 + l
    int l = (int)(bl & (Ll - 1));
    int b = (int)(bl >> 11);
    float acc = 0.0f;
#pragma unroll
    for (int k = 0; k < DCONV; ++k) {
        int t = l + k - (DCONV - 1);
        if (t >= 0)
            acc = fmaf(xz[((size_t)(b * Ll + t)) * (2 * DINNER) + d],
                       dwk[k * DINNER + d], acc);
    }
    xc_pre[i] = acc;
}

// ---------------------------------------------------------------------------
// Selective scan, chunked. Pass 1: per-chunk local scan (h_in = 0),
// emits cumulative dA product and local final h per (b,chunk,n,d).
// grid: (DINNER/256, NCH, Bb)
// ---------------------------------------------------------------------------
__global__ __launch_bounds__(256) void scan_pass1(
    const float* __restrict__ delta, const float* __restrict__ xc,
    const float* __restrict__ xdbl, const float* __restrict__ A_log,
    float* __restrict__ cs_a, float* __restrict__ cs_h)
{
    const int d = blockIdx.x * 256 + threadIdx.x;
    const int c = blockIdx.y;
    const int b = blockIdx.z;
    const int t0 = c * CL;

    __shared__ float sB[CL][8];
    {
        int i = threadIdx.x;   // CL*8 == 256
        int t = i >> 3, j = i & 7;
        sB[t][j] = xdbl[((size_t)(b * Ll + t0 + t)) * 80 + DTRANK + j];
    }
    __syncthreads();

    float An[8];
#pragma unroll
    for (int n = 0; n < 8; ++n) An[n] = -__expf(A_log[d * 8 + n]);

    float h[8], ap[8];
#pragma unroll
    for (int n = 0; n < 8; ++n) { h[n] = 0.0f; ap[n] = 1.0f; }

    const float* dptr = delta + ((size_t)(b * Ll + t0)) * DINNER + d;
    const float* xptr = xc + ((size_t)(b * Ll + t0)) * DINNER + d;

#pragma unroll 4
    for (int t = 0; t < CL; ++t) {
        float dl = dptr[(size_t)t * DINNER];
        float xv = xptr[(size_t)t * DINNER];
        float du = dl * xv;
#pragma unroll
        for (int n = 0; n < 8; ++n) {
            float dA = __expf(dl * An[n]);
            h[n] = fmaf(dA, h[n], du * sB[t][n]);
            ap[n] *= dA;
        }
    }

    size_t base = (((size_t)(b * NCH + c)) * 8) * DINNER + d;
#pragma unroll
    for (int n = 0; n < 8; ++n) {
        cs_a[base + (size_t)n * DINNER] = ap[n];
        cs_h[base + (size_t)n * DINNER] = h[n];
    }
}

// Pass 2: sequential combine across chunks per (b,n,d); writes exclusive
// prefix h_in per chunk. 32768 threads.
__global__ __launch_bounds__(256) void scan_pass2(
    const float* __restrict__ cs_a, const float* __restrict__ cs_h,
    float* __restrict__ hin)
{
    int idx = blockIdx.x * 256 + threadIdx.x;
    if (idx >= Bb * 8 * DINNER) return;
    int d = idx & (DINNER - 1);
    int n = (idx >> 11) & 7;
    int b = idx >> 14;
    float H = 0.0f;
    for (int c = 0; c < NCH; ++c) {
        size_t o = (((size_t)(b * NCH + c)) * 8 + n) * DINNER + d;
        hin[o] = H;
        H = fmaf(cs_a[o], H, cs_h[o]);
    }
}

// Pass 3: replay chunk with correct h_in, compute y_t = C·h, then fused
// y = (y_t + xc*D) * silu(z); writes y IN PLACE over delta (same index,
// same thread, read-before-write) — dy is intentionally not restrict.
__global__ __launch_bounds__(256) void scan_pass3(
    float* dy,                                   // delta in, y out (aliased)
    const float* __restrict__ xc, const float* __restrict__ xdbl,
    const float* __restrict__ A_log, const float* __restrict__ hin,
    const float* __restrict__ xz, const float* __restrict__ Dvec)
{
    const int d = blockIdx.x * 256 + threadIdx.x;
    const int c = blockIdx.y;
    const int b = blockIdx.z;
    const int t0 = c * CL;

    __shared__ float sB[CL][8];
    __shared__ float sC[CL][8];
    {
        int i = threadIdx.x;   // CL*16 == 512 loads, 256 threads: 2 each
        int t = i >> 4, j = i & 15;
        float v = xdbl[((size_t)(b * Ll + t0 + t)) * 80 + DTRANK + j];
        if (j < 8) sB[t][j] = v; else sC[t][j - 8] = v;
        t = (i + 256) >> 4; j = (i + 256) & 15;
        v = xdbl[((size_t)(b * Ll + t0 + t)) * 80 + DTRANK + j];
        if (j < 8) sB[t][j] = v; else sC[t][j - 8] = v;
    }
    __syncthreads();

    float An[8];
#pragma unroll
    for (int n = 0; n < 8; ++n) An[n] = -__expf(A_log[d * 8 + n]);

    float h[8];
    size_t hbase = (((size_t)(b * NCH + c)) * 8) * DINNER + d;
#pragma unroll
    for (int n = 0; n < 8; ++n) h[n] = hin[hbase + (size_t)n * DINNER];

    const float Dd = Dvec[d];
    float* dptr = dy + ((size_t)(b * Ll + t0)) * DINNER + d;
    const float* xptr = xc + ((size_t)(b * Ll + t0)) * DINNER + d;
    const float* zptr = xz + ((size_t)(b * Ll + t0)) * (2 * DINNER) + DINNER + d;

    for (int t = 0; t < CL; ++t) {
        float dl = dptr[(size_t)t * DINNER];
        float xv = xptr[(size_t)t * DINNER];
        float du = dl * xv;
        float yt = 0.0f;
#pragma unroll
        for (int n = 0; n < 8; ++n) {
            float dA = __expf(dl * An[n]);
            h[n] = fmaf(dA, h[n], du * sB[t][n]);
            yt = fmaf(sC[t][n], h[n], yt);
        }
        float zv = zptr[(size_t)t * (2 * DINNER)];
        dptr[(size_t)t * DINNER] = (yt + xv * Dd) * silu_f(zv);
    }
}

// ---------------------------------------------------------------------------
extern "C" void kernel_launch(void* const* d_in, const int* in_sizes, int n_in,
                              void* d_out, int out_size, void* d_ws, size_t ws_size,
                              hipStream_t stream)
{
    const float* x         = (const float*)d_in[0];
    const float* W_in      = (const float*)d_in[1];
    const float* dwk       = (const float*)d_in[2];
    const float* pwk       = (const float*)d_in[3];
    const float* conv_bias = (const float*)d_in[4];
    const float* W_x       = (const float*)d_in[5];
    const float* W_dt      = (const float*)d_in[6];
    const float* b_dt      = (const float*)d_in[7];
    const float* A_log     = (const float*)d_in[8];
    const float* Dv        = (const float*)d_in[9];
    const float* W_out     = (const float*)d_in[10];
    float* out = (float*)d_out;

    char* ws = (char*)d_ws;
    float* xz     = (float*)(ws);                      // 64 MB (b,l,4096)
    float* xc_pre = (float*)(ws + (64ull  << 20));     // 32 MB
    float* xc     = (float*)(ws + (96ull  << 20));     // 32 MB
    float* xdbl   = (float*)(ws + (128ull << 20));     // 1.25 MB (b,l,80)
    float* cs_a   = (float*)(ws + (130ull << 20));     // 8 MB
    float* cs_h   = (float*)(ws + (138ull << 20));     // 8 MB
    float* hin    = (float*)(ws + (146ull << 20));     // 8 MB
    float* delta  = xc_pre;   // xc_pre dead after G2 -> reuse for delta
    float* y      = delta;    // y written in place over delta in pass 3

    dim3 blk(256);

    // G1: xz = x @ W_in   (4096x1024 @ 1024x4096)
    gemm_tiled<0><<<dim3(64, 64), blk, 0, stream>>>(
        x, W_in, xz, MM, 2 * DINNER, DMODEL, DMODEL, 2 * DINNER, 2 * DINNER, nullptr);

    // depthwise causal conv on x_in half of xz
    dwconv_kernel<<<(MM * DINNER + 255) / 256, blk, 0, stream>>>(xz, dwk, xc_pre);

    // G2: xc = silu(xc_pre @ pw + conv_bias)   (4096x2048 @ 2048x2048)
    gemm_tiled<1><<<dim3(32, 64), blk, 0, stream>>>(
        xc_pre, pwk, xc, MM, DINNER, DINNER, DINNER, DINNER, DINNER, conv_bias);

    // G3: x_dbl = xc @ W_x   (4096x2048 @ 2048x80)
    gemm_tiled<0><<<dim3(2, 64), blk, 0, stream>>>(
        xc, W_x, xdbl, MM, 80, DINNER, DINNER, 80, 80, nullptr);

    // G4: delta = softplus(x_dbl[:, :64] @ W_dt + b_dt)  (4096x64 @ 64x2048)
    gemm_tiled<2><<<dim3(32, 64), blk, 0, stream>>>(
        xdbl, W_dt, delta, MM, DINNER, DTRANK, 80, DINNER, DINNER, b_dt);

    // selective scan, 3-pass chunked
    scan_pass1<<<dim3(DINNER / 256, NCH, Bb), blk, 0, stream>>>(
        delta, xc, xdbl, A_log, cs_a, cs_h);
    scan_pass2<<<(Bb * 8 * DINNER + 255) / 256, blk, 0, stream>>>(cs_a, cs_h, hin);
    scan_pass3<<<dim3(DINNER / 256, NCH, Bb), blk, 0, stream>>>(
        y, xc, xdbl, A_log, hin, xz, Dv);

    // G5: out = y @ W_out   (4096x2048 @ 2048x1024)
    gemm_tiled<0><<<dim3(16, 64), blk, 0, stream>>>(
        y, W_out, out, MM, DMODEL, DINNER, DINNER, DMODEL, DMODEL, nullptr);
}

// Round 3
// 580.715 us; speedup vs baseline: 2.7056x; 2.7056x over previous
//
#include <hip/hip_runtime.h>
#include <math.h>

// Problem constants
#define Bb 2
#define Ll 2048
#define DMODEL 1024
#define DINNER 2048
#define DSTATE 8
#define DTRANK 64
#define DCONV 4
#define MM (Bb*Ll)          // 4096 rows
// scan chunking
#define NCH 64
#define CL 32               // NCH*CL == Ll

typedef __attribute__((ext_vector_type(8))) short    bf16x8;
typedef __attribute__((ext_vector_type(8))) unsigned short u16x8;
typedef __attribute__((ext_vector_type(4))) float    f32x4;

__device__ __forceinline__ float silu_f(float x) {
    return x / (1.0f + __expf(-x));
}
__device__ __forceinline__ float softplus_f(float x) {
    return fmaxf(x, 0.0f) + log1pf(__expf(-fabsf(x)));
}
__device__ __forceinline__ unsigned short f2bf(float f) {
    unsigned int u = __float_as_uint(f);
    u += 0x7fffu + ((u >> 16) & 1u);      // RNE
    return (unsigned short)(u >> 16);
}

// ---------------------------------------------------------------------------
// bf16 MFMA GEMM: C[M,N] = epi(A[M,K] @ Bt[N,K]^T + bias)
// A, Bt bf16 row-major; C fp32. 128x128 block, 4 waves, BK=32.
// All dims assumed multiples of the tile (true for every call site).
// EPI: 0 = none, 1 = silu(x + bias[n])
// ---------------------------------------------------------------------------
template <int EPI>
__global__ __launch_bounds__(256) void mfma_gemm(
    const unsigned short* __restrict__ A, const unsigned short* __restrict__ Bt,
    float* __restrict__ C, int M, int N, int K,
    int lda, int ldb, int ldc, const float* __restrict__ bias)
{
    __shared__ unsigned short As[128][40];  // 32 data + 8 pad (80B rows, 16B-aligned)
    __shared__ unsigned short Bs[128][40];

    const int bm = blockIdx.y * 128;
    const int bn = blockIdx.x * 128;
    const int tid  = threadIdx.x;
    const int w    = tid >> 6;          // wave 0..3
    const int lane = tid & 63;
    const int wm = (w >> 1) * 64;
    const int wn = (w & 1) * 64;
    const int lr = lane & 15;           // row within 16x16 tile
    const int lq = lane >> 4;           // quad -> k-offset lq*8, out-row lq*4

    // staging mapping: 4 threads per 32-elem (64B) row
    const int srow = tid >> 2;          // 0..63
    const int skc  = (tid & 3) * 8;

    const unsigned short* Ag = A  + (size_t)(bm + srow) * lda + skc;
    const unsigned short* Bg = Bt + (size_t)(bn + srow) * ldb + skc;

    f32x4 acc[4][4];
#pragma unroll
    for (int i = 0; i < 4; ++i)
#pragma unroll
        for (int j = 0; j < 4; ++j) acc[i][j] = (f32x4){0.f, 0.f, 0.f, 0.f};

    for (int k0 = 0; k0 < K; k0 += 32) {
        __syncthreads();   // previous compute done before overwrite
        *(u16x8*)&As[srow][skc]      = *(const u16x8*)(Ag + k0);
        *(u16x8*)&As[srow + 64][skc] = *(const u16x8*)(Ag + (size_t)64 * lda + k0);
        *(u16x8*)&Bs[srow][skc]      = *(const u16x8*)(Bg + k0);
        *(u16x8*)&Bs[srow + 64][skc] = *(const u16x8*)(Bg + (size_t)64 * ldb + k0);
        __syncthreads();

        bf16x8 a[4], b[4];
#pragma unroll
        for (int i = 0; i < 4; ++i)
            a[i] = *(const bf16x8*)&As[wm + i * 16 + lr][lq * 8];
#pragma unroll
        for (int j = 0; j < 4; ++j)
            b[j] = *(const bf16x8*)&Bs[wn + j * 16 + lr][lq * 8];
#pragma unroll
        for (int i = 0; i < 4; ++i)
#pragma unroll
            for (int j = 0; j < 4; ++j)
                acc[i][j] = __builtin_amdgcn_mfma_f32_16x16x32_bf16(
                    a[i], b[j], acc[i][j], 0, 0, 0);
    }

    // epilogue: C/D layout col = lane&15, row = (lane>>4)*4 + reg
#pragma unroll
    for (int i = 0; i < 4; ++i) {
        const int row0 = bm + wm + i * 16 + lq * 4;
#pragma unroll
        for (int j = 0; j < 4; ++j) {
            const int col = bn + wn + j * 16 + lr;
            float bv = (EPI == 1) ? bias[col] : 0.0f;
#pragma unroll
            for (int r = 0; r < 4; ++r) {
                float v = acc[i][j][r];
                if (EPI == 1) v = silu_f(v + bv);
                C[(size_t)(row0 + r) * ldc + col] = v;
            }
        }
    }
}

// ---------------------------------------------------------------------------
// fp32 tiled GEMM (kept for small G3/G4): C = epi(A@B + bias)
// EPI: 0 none, 2 softplus(x + bias[n])
// ---------------------------------------------------------------------------
template <int EPI>
__global__ __launch_bounds__(256) void gemm_tiled(
    const float* __restrict__ A, const float* __restrict__ B,
    float* __restrict__ C, int M, int N, int K,
    int lda, int ldb, int ldc, const float* __restrict__ bias)
{
    __shared__ float As[16][68];
    __shared__ float Bs[16][68];

    const int bm = blockIdx.y * 64;
    const int bn = blockIdx.x * 64;
    const int tid = threadIdx.x;
    const int tx = tid & 15;
    const int ty = tid >> 4;

    float acc[4][4];
#pragma unroll
    for (int i = 0; i < 4; ++i)
#pragma unroll
        for (int j = 0; j < 4; ++j) acc[i][j] = 0.0f;

    const int ar = tid >> 2;
    const int ac = (tid & 3) << 2;
    const int br = tid >> 4;
    const int bc = (tid & 15) << 2;

    for (int k0 = 0; k0 < K; k0 += 16) {
        float4 av = make_float4(0.f, 0.f, 0.f, 0.f);
        if (bm + ar < M)
            av = *(const float4*)&A[(size_t)(bm + ar) * lda + k0 + ac];
        As[ac + 0][ar] = av.x;
        As[ac + 1][ar] = av.y;
        As[ac + 2][ar] = av.z;
        As[ac + 3][ar] = av.w;

        float4 bv = make_float4(0.f, 0.f, 0.f, 0.f);
        if (bn + bc < N)
            bv = *(const float4*)&B[(size_t)(k0 + br) * ldb + bn + bc];
        *(float4*)&Bs[br][bc] = bv;

        __syncthreads();
#pragma unroll
        for (int k = 0; k < 16; ++k) {
            float4 a4 = *(float4*)&As[k][ty * 4];
            float4 b4 = *(float4*)&Bs[k][tx * 4];
            float am[4] = {a4.x, a4.y, a4.z, a4.w};
            float bn4[4] = {b4.x, b4.y, b4.z, b4.w};
#pragma unroll
            for (int i = 0; i < 4; ++i)
#pragma unroll
                for (int j = 0; j < 4; ++j)
                    acc[i][j] = fmaf(am[i], bn4[j], acc[i][j]);
        }
        __syncthreads();
    }

    const int col = bn + tx * 4;
    if (col >= N) return;
#pragma unroll
    for (int i = 0; i < 4; ++i) {
        int row = bm + ty * 4 + i;
        if (row >= M) continue;
        float4 v = make_float4(acc[i][0], acc[i][1], acc[i][2], acc[i][3]);
        if (EPI == 2) {
            v.x = softplus_f(v.x + bias[col + 0]);
            v.y = softplus_f(v.y + bias[col + 1]);
            v.z = softplus_f(v.z + bias[col + 2]);
            v.w = softplus_f(v.w + bias[col + 3]);
        }
        *(float4*)&C[(size_t)row * ldc + col] = v;
    }
}

// ---------------------------------------------------------------------------
// transpose + fp32->bf16 cast: src[R][C] fp32 -> dst[C][R] bf16
// ---------------------------------------------------------------------------
__global__ __launch_bounds__(256) void transpose_cast(
    const float* __restrict__ src, unsigned short* __restrict__ dst, int R, int C)
{
    __shared__ float tile[32][33];
    const int c0 = blockIdx.x * 32;
    const int r0 = blockIdx.y * 32;
    const int tx = threadIdx.x;       // 0..31
    const int ty = threadIdx.y;       // 0..7
#pragma unroll
    for (int i = 0; i < 32; i += 8)
        tile[ty + i][tx] = src[(size_t)(r0 + ty + i) * C + c0 + tx];
    __syncthreads();
#pragma unroll
    for (int i = 0; i < 32; i += 8)
        dst[(size_t)(c0 + ty + i) * R + r0 + tx] = f2bf(tile[tx][ty + i]);
}

// elementwise fp32->bf16 cast (4 per thread)
__global__ __launch_bounds__(256) void cast_bf16(
    const float* __restrict__ src, unsigned short* __restrict__ dst, int n)
{
    int i = (blockIdx.x * 256 + threadIdx.x) * 4;
    if (i >= n) return;
    float4 v = *(const float4*)&src[i];
    ushort4 o;
    o.x = f2bf(v.x); o.y = f2bf(v.y); o.z = f2bf(v.z); o.w = f2bf(v.w);
    *(ushort4*)&dst[i] = o;
}

// ---------------------------------------------------------------------------
// Depthwise causal conv, k=4, on contiguous x_in [M][DINNER]; bf16 output.
// ---------------------------------------------------------------------------
__global__ __launch_bounds__(256) void dwconv_kernel(
    const float* __restrict__ x_in, const float* __restrict__ dwk,
    unsigned short* __restrict__ out)
{
    size_t i = (size_t)blockIdx.x * 256 + threadIdx.x;
    if (i >= (size_t)MM * DINNER) return;
    int d = (int)(i & (DINNER - 1));
    size_t bl = i >> 11;
    int l = (int)(bl & (Ll - 1));
    int b = (int)(bl >> 11);
    float acc = 0.0f;
#pragma unroll
    for (int k = 0; k < DCONV; ++k) {
        int t = l + k - (DCONV - 1);
        if (t >= 0)
            acc = fmaf(x_in[((size_t)(b * Ll + t)) * DINNER + d],
                       dwk[k * DINNER + d], acc);
    }
    out[i] = f2bf(acc);
}

// ---------------------------------------------------------------------------
// Selective scan pass 1: per-chunk local scan from h=0.
// ---------------------------------------------------------------------------
__global__ __launch_bounds__(256) void scan_pass1(
    const float* __restrict__ delta, const float* __restrict__ xc,
    const float* __restrict__ xdbl, const float* __restrict__ A_log,
    float* __restrict__ cs_a, float* __restrict__ cs_h)
{
    const int d = blockIdx.x * 256 + threadIdx.x;
    const int c = blockIdx.y;
    const int b = blockIdx.z;
    const int t0 = c * CL;

    __shared__ float sB[CL][8];
    {
        int i = threadIdx.x;
        int t = i >> 3, j = i & 7;
        sB[t][j] = xdbl[((size_t)(b * Ll + t0 + t)) * 80 + DTRANK + j];
    }
    __syncthreads();

    float An[8];
#pragma unroll
    for (int n = 0; n < 8; ++n) An[n] = -__expf(A_log[d * 8 + n]);

    float h[8], ap[8];
#pragma unroll
    for (int n = 0; n < 8; ++n) { h[n] = 0.0f; ap[n] = 1.0f; }

    const float* dptr = delta + ((size_t)(b * Ll + t0)) * DINNER + d;
    const float* xptr = xc + ((size_t)(b * Ll + t0)) * DINNER + d;

#pragma unroll 4
    for (int t = 0; t < CL; ++t) {
        float dl = dptr[(size_t)t * DINNER];
        float xv = xptr[(size_t)t * DINNER];
        float du = dl * xv;
#pragma unroll
        for (int n = 0; n < 8; ++n) {
            float dA = __expf(dl * An[n]);
            h[n] = fmaf(dA, h[n], du * sB[t][n]);
            ap[n] *= dA;
        }
    }

    size_t base = (((size_t)(b * NCH + c)) * 8) * DINNER + d;
#pragma unroll
    for (int n = 0; n < 8; ++n) {
        cs_a[base + (size_t)n * DINNER] = ap[n];
        cs_h[base + (size_t)n * DINNER] = h[n];
    }
}

// Pass 2: sequential combine; hin may ALIAS cs_h (in-place) — read-before-write.
__global__ __launch_bounds__(256) void scan_pass2(
    const float* __restrict__ cs_a, const float* cs_h, float* hin)
{
    int idx = blockIdx.x * 256 + threadIdx.x;
    if (idx >= Bb * 8 * DINNER) return;
    int d = idx & (DINNER - 1);
    int n = (idx >> 11) & 7;
    int b = idx >> 14;
    float H = 0.0f;
    for (int c = 0; c < NCH; ++c) {
        size_t o = (((size_t)(b * NCH + c)) * 8 + n) * DINNER + d;
        float a = cs_a[o];
        float hh = cs_h[o];
        hin[o] = H;
        H = fmaf(a, H, hh);
    }
}

// Pass 3: replay with correct h_in; fused epilogue -> bf16 y.
__global__ __launch_bounds__(256) void scan_pass3(
    const float* __restrict__ delta, const float* __restrict__ xc,
    const float* __restrict__ xdbl, const float* __restrict__ A_log,
    const float* __restrict__ hin, const float* __restrict__ z,
    const float* __restrict__ Dvec, unsigned short* __restrict__ y_bf)
{
    const int d = blockIdx.x * 256 + threadIdx.x;
    const int c = blockIdx.y;
    const int b = blockIdx.z;
    const int t0 = c * CL;

    __shared__ float sB[CL][8];
    __shared__ float sC[CL][8];
    {
        int i = threadIdx.x;
        int t = i >> 4, j = i & 15;
        float v = xdbl[((size_t)(b * Ll + t0 + t)) * 80 + DTRANK + j];
        if (j < 8) sB[t][j] = v; else sC[t][j - 8] = v;
        t = (i + 256) >> 4; j = (i + 256) & 15;
        v = xdbl[((size_t)(b * Ll + t0 + t)) * 80 + DTRANK + j];
        if (j < 8) sB[t][j] = v; else sC[t][j - 8] = v;
    }
    __syncthreads();

    float An[8];
#pragma unroll
    for (int n = 0; n < 8; ++n) An[n] = -__expf(A_log[d * 8 + n]);

    float h[8];
    size_t hbase = (((size_t)(b * NCH + c)) * 8) * DINNER + d;
#pragma unroll
    for (int n = 0; n < 8; ++n) h[n] = hin[hbase + (size_t)n * DINNER];

    const float Dd = Dvec[d];
    const float* dptr = delta + ((size_t)(b * Ll + t0)) * DINNER + d;
    const float* xptr = xc + ((size_t)(b * Ll + t0)) * DINNER + d;
    const float* zptr = z + ((size_t)(b * Ll + t0)) * DINNER + d;
    unsigned short* yptr = y_bf + ((size_t)(b * Ll + t0)) * DINNER + d;

    for (int t = 0; t < CL; ++t) {
        float dl = dptr[(size_t)t * DINNER];
        float xv = xptr[(size_t)t * DINNER];
        float du = dl * xv;
        float yt = 0.0f;
#pragma unroll
        for (int n = 0; n < 8; ++n) {
            float dA = __expf(dl * An[n]);
            h[n] = fmaf(dA, h[n], du * sB[t][n]);
            yt = fmaf(sC[t][n], h[n], yt);
        }
        float zv = zptr[(size_t)t * DINNER];
        yptr[(size_t)t * DINNER] = f2bf((yt + xv * Dd) * silu_f(zv));
    }
}

// ---------------------------------------------------------------------------
extern "C" void kernel_launch(void* const* d_in, const int* in_sizes, int n_in,
                              void* d_out, int out_size, void* d_ws, size_t ws_size,
                              hipStream_t stream)
{
    const float* x         = (const float*)d_in[0];
    const float* W_in      = (const float*)d_in[1];
    const float* dwk       = (const float*)d_in[2];
    const float* pwk       = (const float*)d_in[3];
    const float* conv_bias = (const float*)d_in[4];
    const float* W_x       = (const float*)d_in[5];
    const float* W_dt      = (const float*)d_in[6];
    const float* b_dt      = (const float*)d_in[7];
    const float* A_log     = (const float*)d_in[8];
    const float* Dv        = (const float*)d_in[9];
    const float* W_out     = (const float*)d_in[10];
    float* out = (float*)d_out;

    // workspace map (bytes; 138 MB total, <= proven 154 MB)
    char* ws = (char*)d_ws;
    float*          x_in   = (float*)(ws);                          // 32 MB, dies after dwconv
    float*          delta  = (float*)(ws);                          //  reuses x_in slot
    float*          z      = (float*)(ws + (32ull  << 20));         // 32 MB
    unsigned short* x_bf   = (unsigned short*)(ws + (64ull << 20)); //  8 MB \ die after G1;
    unsigned short* Wint   = (unsigned short*)(ws + (72ull << 20)); //  8 MB /  y_bf reuses
    unsigned short* y_bf   = (unsigned short*)(ws + (64ull << 20)); // 16 MB (over x_bf+Wint)
    unsigned short* pw_t   = (unsigned short*)(ws + (80ull << 20)); //  8 MB, dies after G2
    unsigned short* Woutt  = (unsigned short*)(ws + (80ull << 20)); //  4 MB (over pw_t)
    float*          xc     = (float*)(ws + (88ull  << 20));         // 32 MB
    unsigned short* xcp_bf = (unsigned short*)(ws + (120ull << 20));// 16 MB, dies after G2
    float*          cs_a   = (float*)(ws + (120ull << 20));         //  8 MB (over xcp_bf)
    float*          cs_h   = (float*)(ws + (128ull << 20));         //  8 MB; hin in-place
    float*          xdbl   = (float*)(ws + (136ull << 20));         //  2 MB slot
    float*          hin    = cs_h;

    dim3 blk(256);

    // operand prep
    cast_bf16<<<(MM * DMODEL / 4 + 255) / 256, blk, 0, stream>>>(x, x_bf, MM * DMODEL);
    // W_in [DMODEL][2*DINNER]: grid.x = C/32 = (2*DINNER)/32 = 128  (was 4*DINNER/32: OOB!)
    transpose_cast<<<dim3((2 * DINNER) / 32, DMODEL / 32), dim3(32, 8), 0, stream>>>(
        W_in, Wint, DMODEL, 2 * DINNER);          // [1024][4096] -> [4096][1024]
    transpose_cast<<<dim3(DINNER / 32, DINNER / 32), dim3(32, 8), 0, stream>>>(
        pwk, pw_t, DINNER, DINNER);               // [2048][2048] -> [2048][2048]

    // G1a/G1b: x @ W_in split into x_in and z halves (bf16 MFMA)
    mfma_gemm<0><<<dim3(DINNER / 128, MM / 128), blk, 0, stream>>>(
        x_bf, Wint, x_in, MM, DINNER, DMODEL, DMODEL, DMODEL, DINNER, nullptr);
    mfma_gemm<0><<<dim3(DINNER / 128, MM / 128), blk, 0, stream>>>(
        x_bf, Wint + (size_t)DINNER * DMODEL, z, MM, DINNER, DMODEL,
        DMODEL, DMODEL, DINNER, nullptr);

    // depthwise causal conv (reads fp32 x_in, emits bf16)
    dwconv_kernel<<<(MM * DINNER + 255) / 256, blk, 0, stream>>>(x_in, dwk, xcp_bf);

    // G2: xc = silu(conv @ pw + conv_bias)  (bf16 MFMA, fp32 out)
    mfma_gemm<1><<<dim3(DINNER / 128, MM / 128), blk, 0, stream>>>(
        xcp_bf, pw_t, xc, MM, DINNER, DINNER, DINNER, DINNER, DINNER, conv_bias);

    // W_out transpose (pw_t slot now dead)
    transpose_cast<<<dim3(DMODEL / 32, DINNER / 32), dim3(32, 8), 0, stream>>>(
        W_out, Woutt, DINNER, DMODEL);            // [2048][1024] -> [1024][2048]

    // G3: x_dbl = xc @ W_x  (fp32, small N)
    gemm_tiled<0><<<dim3(2, MM / 64), blk, 0, stream>>>(
        xc, W_x, xdbl, MM, 80, DINNER, DINNER, 80, 80, nullptr);

    // G4: delta = softplus(x_dbl[:, :64] @ W_dt + b_dt)  (fp32; overwrites x_in slot)
    gemm_tiled<2><<<dim3(DINNER / 64, MM / 64), blk, 0, stream>>>(
        xdbl, W_dt, delta, MM, DINNER, DTRANK, 80, DINNER, DINNER, b_dt);

    // selective scan, 3-pass chunked
    scan_pass1<<<dim3(DINNER / 256, NCH, Bb), blk, 0, stream>>>(
        delta, xc, xdbl, A_log, cs_a, cs_h);
    scan_pass2<<<(Bb * 8 * DINNER + 255) / 256, blk, 0, stream>>>(cs_a, cs_h, hin);
    scan_pass3<<<dim3(DINNER / 256, NCH, Bb), blk, 0, stream>>>(
        delta, xc, xdbl, A_log, hin, z, Dv, y_bf);

    // G5: out = y @ W_out  (bf16 MFMA)
    mfma_gemm<0><<<dim3(DMODEL / 128, MM / 128), blk, 0, stream>>>(
        y_bf, Woutt, out, MM, DMODEL, DINNER, DINNER, DINNER, DMODEL, nullptr);
}

// Round 4
// 439.051 us; speedup vs baseline: 3.5786x; 1.3227x over previous
//
#include <hip/hip_runtime.h>
#include <math.h>

// Problem constants
#define Bb 2
#define Ll 2048
#define DMODEL 1024
#define DINNER 2048
#define DSTATE 8
#define DTRANK 64
#define DCONV 4
#define MM (Bb*Ll)          // 4096 rows
// scan chunking
#define NCH 64
#define CL 32               // NCH*CL == Ll
// G3 split-K
#define G3_KCH 8
#define G3_KC (DINNER / G3_KCH)   // 256

typedef __attribute__((ext_vector_type(8))) short    bf16x8;
typedef __attribute__((ext_vector_type(4))) float    f32x4;

__device__ __forceinline__ float silu_f(float x) {
    return x / (1.0f + __expf(-x));
}
__device__ __forceinline__ float softplus_f(float x) {
    return fmaxf(x, 0.0f) + log1pf(__expf(-fabsf(x)));
}
__device__ __forceinline__ unsigned short f2bf(float f) {
    unsigned int u = __float_as_uint(f);
    u += 0x7fffu + ((u >> 16) & 1u);      // RNE
    return (unsigned short)(u >> 16);
}
// async 16B global->LDS (wave-uniform LDS base + lane*16 dest)
__device__ __forceinline__ void async_cp16(const unsigned short* g, unsigned short* l) {
    __builtin_amdgcn_global_load_lds(
        (const __attribute__((address_space(1))) void*)g,
        (__attribute__((address_space(3))) void*)l, 16, 0, 0);
}

// ---------------------------------------------------------------------------
// bf16 MFMA GEMM: C[M,N] = epi(A[M,K] @ Bt[N,K]^T + bias)
// 128x128 block, 4 waves, BK=32. Staging via global_load_lds width=16 into
// FLAT (unpadded) LDS [128][32]; 16B-slot XOR swizzle (slot ^ ((row>>1)&3))
// applied on the GLOBAL side so ds_read_b128 is only 2-way bank-aliased.
// EPI: 0 = none, 1 = silu(x + bias[n])
// ---------------------------------------------------------------------------
template <int EPI>
__global__ __launch_bounds__(256) void mfma_gemm(
    const unsigned short* __restrict__ A, const unsigned short* __restrict__ Bt,
    float* __restrict__ C, int M, int N, int K,
    int lda, int ldb, int ldc, const float* __restrict__ bias)
{
    __shared__ unsigned short As[128 * 32];   // 8 KB, flat: row*32 + physslot*8
    __shared__ unsigned short Bs[128 * 32];

    const int bm = blockIdx.y * 128;
    const int bn = blockIdx.x * 128;
    const int tid  = threadIdx.x;
    const int w    = tid >> 6;          // wave 0..3
    const int lane = tid & 63;
    const int wm = (w >> 1) * 64;
    const int wn = (w & 1) * 64;
    const int lr = lane & 15;
    const int lq = lane >> 4;

    // staging: each wave fills rows [w*32, w*32+32); 2 issues per operand.
    // issue covers 16 rows: row = w*32 + lane/4 (+16), physslot = lane&3.
    const int r1 = w * 32 + (lane >> 2);
    const int sp = lane & 3;
    const int slog = sp ^ ((r1 >> 1) & 3);   // same for r1 and r1+16
    const unsigned short* gA1 = A  + (size_t)(bm + r1) * lda + slog * 8;
    const unsigned short* gA2 = gA1 + (size_t)16 * lda;
    const unsigned short* gB1 = Bt + (size_t)(bn + r1) * ldb + slog * 8;
    const unsigned short* gB2 = gB1 + (size_t)16 * ldb;
    unsigned short* lA1 = As + w * 1024;          // 32 rows * 32 elems
    unsigned short* lA2 = As + w * 1024 + 512;
    unsigned short* lB1 = Bs + w * 1024;
    unsigned short* lB2 = Bs + w * 1024 + 512;

    // fragment read offsets (logical slot lq lives at phys slot lq^((lr>>1)&3))
    const int fsw = (lq ^ ((lr >> 1) & 3)) * 8;

    f32x4 acc[4][4];
#pragma unroll
    for (int i = 0; i < 4; ++i)
#pragma unroll
        for (int j = 0; j < 4; ++j) acc[i][j] = (f32x4){0.f, 0.f, 0.f, 0.f};

    for (int k0 = 0; k0 < K; k0 += 32) {
        __syncthreads();   // previous iter's LDS reads done
        async_cp16(gA1 + k0, lA1);
        async_cp16(gA2 + k0, lA2);
        async_cp16(gB1 + k0, lB1);
        async_cp16(gB2 + k0, lB2);
        __syncthreads();   // drains vmcnt before barrier -> staging complete

        bf16x8 a[4], b[4];
#pragma unroll
        for (int i = 0; i < 4; ++i)
            a[i] = *(const bf16x8*)&As[(wm + i * 16 + lr) * 32 + fsw];
#pragma unroll
        for (int j = 0; j < 4; ++j)
            b[j] = *(const bf16x8*)&Bs[(wn + j * 16 + lr) * 32 + fsw];
#pragma unroll
        for (int i = 0; i < 4; ++i)
#pragma unroll
            for (int j = 0; j < 4; ++j)
                acc[i][j] = __builtin_amdgcn_mfma_f32_16x16x32_bf16(
                    a[i], b[j], acc[i][j], 0, 0, 0);
    }

    // epilogue: C/D layout col = lane&15, row = (lane>>4)*4 + reg
#pragma unroll
    for (int i = 0; i < 4; ++i) {
        const int row0 = bm + wm + i * 16 + lq * 4;
#pragma unroll
        for (int j = 0; j < 4; ++j) {
            const int col = bn + wn + j * 16 + lr;
            float bv = (EPI == 1) ? bias[col] : 0.0f;
#pragma unroll
            for (int r = 0; r < 4; ++r) {
                float v = acc[i][j][r];
                if (EPI == 1) v = silu_f(v + bv);
                C[(size_t)(row0 + r) * ldc + col] = v;
            }
        }
    }
}

// ---------------------------------------------------------------------------
// fp32 tiled GEMM (G4 only): C = softplus(A@B + bias)
// ---------------------------------------------------------------------------
__global__ __launch_bounds__(256) void gemm_tiled_sp(
    const float* __restrict__ A, const float* __restrict__ B,
    float* __restrict__ C, int M, int N, int K,
    int lda, int ldb, int ldc, const float* __restrict__ bias)
{
    __shared__ float As[16][68];
    __shared__ float Bs[16][68];

    const int bm = blockIdx.y * 64;
    const int bn = blockIdx.x * 64;
    const int tid = threadIdx.x;
    const int tx = tid & 15;
    const int ty = tid >> 4;

    float acc[4][4];
#pragma unroll
    for (int i = 0; i < 4; ++i)
#pragma unroll
        for (int j = 0; j < 4; ++j) acc[i][j] = 0.0f;

    const int ar = tid >> 2;
    const int ac = (tid & 3) << 2;
    const int br = tid >> 4;
    const int bc = (tid & 15) << 2;

    for (int k0 = 0; k0 < K; k0 += 16) {
        float4 av = *(const float4*)&A[(size_t)(bm + ar) * lda + k0 + ac];
        float4 bv = *(const float4*)&B[(size_t)(k0 + br) * ldb + bn + bc];
        As[ac + 0][ar] = av.x;
        As[ac + 1][ar] = av.y;
        As[ac + 2][ar] = av.z;
        As[ac + 3][ar] = av.w;
        *(float4*)&Bs[br][bc] = bv;
        __syncthreads();
#pragma unroll
        for (int k = 0; k < 16; ++k) {
            float4 a4 = *(float4*)&As[k][ty * 4];
            float4 b4 = *(float4*)&Bs[k][tx * 4];
            float am[4] = {a4.x, a4.y, a4.z, a4.w};
            float bn4[4] = {b4.x, b4.y, b4.z, b4.w};
#pragma unroll
            for (int i = 0; i < 4; ++i)
#pragma unroll
                for (int j = 0; j < 4; ++j)
                    acc[i][j] = fmaf(am[i], bn4[j], acc[i][j]);
        }
        __syncthreads();
    }

    const int col = bn + tx * 4;
#pragma unroll
    for (int i = 0; i < 4; ++i) {
        int row = bm + ty * 4 + i;
        float4 v = make_float4(acc[i][0], acc[i][1], acc[i][2], acc[i][3]);
        v.x = softplus_f(v.x + bias[col + 0]);
        v.y = softplus_f(v.y + bias[col + 1]);
        v.z = softplus_f(v.z + bias[col + 2]);
        v.w = softplus_f(v.w + bias[col + 3]);
        *(float4*)&C[(size_t)row * ldc + col] = v;
    }
}

// ---------------------------------------------------------------------------
// G3 split-K: part[kc][M][80] = xc[:, kc*256:(kc+1)*256] @ W_x-chunk
// grid (MM/64, 8), block 256. Deterministic (no atomics).
// ---------------------------------------------------------------------------
__global__ __launch_bounds__(256) void g3_splitk(
    const float* __restrict__ xc, const float* __restrict__ Wx,
    float* __restrict__ part)
{
    __shared__ float As[16][68];   // [k][row]
    __shared__ float Bs[16][85];   // [k][col], pad to 85 (stride 5 reads)
    const int m0 = blockIdx.x * 64;
    const int kb = blockIdx.y * G3_KC;
    const int t = threadIdx.x;
    const int tr = t >> 4;          // 0..15 -> rows tr*4..tr*4+3
    const int tc = t & 15;          // 0..15 -> cols tc*5..tc*5+4

    const int arow = t >> 2;        // 0..63
    const int ak4  = (t & 3) * 4;
    const int bk   = t >> 4;        // 0..15
    const int bc   = (t & 15) * 5;  // 0..75

    float acc[4][5];
#pragma unroll
    for (int r = 0; r < 4; ++r)
#pragma unroll
        for (int c = 0; c < 5; ++c) acc[r][c] = 0.0f;

    for (int k0 = 0; k0 < G3_KC; k0 += 16) {
        float4 av = *(const float4*)&xc[(size_t)(m0 + arow) * DINNER + kb + k0 + ak4];
        float bv[5];
#pragma unroll
        for (int q = 0; q < 5; ++q)
            bv[q] = Wx[(size_t)(kb + k0 + bk) * 80 + bc + q];
        __syncthreads();
        As[ak4 + 0][arow] = av.x;
        As[ak4 + 1][arow] = av.y;
        As[ak4 + 2][arow] = av.z;
        As[ak4 + 3][arow] = av.w;
#pragma unroll
        for (int q = 0; q < 5; ++q) Bs[bk][bc + q] = bv[q];
        __syncthreads();
#pragma unroll
        for (int k = 0; k < 16; ++k) {
            float a[4], b[5];
#pragma unroll
            for (int r = 0; r < 4; ++r) a[r] = As[k][tr * 4 + r];
#pragma unroll
            for (int c = 0; c < 5; ++c) b[c] = Bs[k][tc * 5 + c];
#pragma unroll
            for (int r = 0; r < 4; ++r)
#pragma unroll
                for (int c = 0; c < 5; ++c)
                    acc[r][c] = fmaf(a[r], b[c], acc[r][c]);
        }
    }
#pragma unroll
    for (int r = 0; r < 4; ++r)
#pragma unroll
        for (int c = 0; c < 5; ++c)
            part[((size_t)blockIdx.y * MM + m0 + tr * 4 + r) * 80 + tc * 5 + c] = acc[r][c];
}

__global__ __launch_bounds__(256) void g3_reduce(
    const float* __restrict__ part, float* __restrict__ xdbl)
{
    int i = (blockIdx.x * 256 + threadIdx.x) * 4;
    if (i >= MM * 80) return;
    float4 s = *(const float4*)&part[i];
#pragma unroll
    for (int c = 1; c < G3_KCH; ++c) {
        float4 p = *(const float4*)&part[(size_t)c * MM * 80 + i];
        s.x += p.x; s.y += p.y; s.z += p.z; s.w += p.w;
    }
    *(float4*)&xdbl[i] = s;
}

// ---------------------------------------------------------------------------
// transpose + fp32->bf16 cast: src[R][C] fp32 -> dst[C][R] bf16
// ---------------------------------------------------------------------------
__global__ __launch_bounds__(256) void transpose_cast(
    const float* __restrict__ src, unsigned short* __restrict__ dst, int R, int C)
{
    __shared__ float tile[32][33];
    const int c0 = blockIdx.x * 32;
    const int r0 = blockIdx.y * 32;
    const int tx = threadIdx.x;
    const int ty = threadIdx.y;
#pragma unroll
    for (int i = 0; i < 32; i += 8)
        tile[ty + i][tx] = src[(size_t)(r0 + ty + i) * C + c0 + tx];
    __syncthreads();
#pragma unroll
    for (int i = 0; i < 32; i += 8)
        dst[(size_t)(c0 + ty + i) * R + r0 + tx] = f2bf(tile[tx][ty + i]);
}

__global__ __launch_bounds__(256) void cast_bf16(
    const float* __restrict__ src, unsigned short* __restrict__ dst, int n)
{
    int i = (blockIdx.x * 256 + threadIdx.x) * 4;
    if (i >= n) return;
    float4 v = *(const float4*)&src[i];
    ushort4 o;
    o.x = f2bf(v.x); o.y = f2bf(v.y); o.z = f2bf(v.z); o.w = f2bf(v.w);
    *(ushort4*)&dst[i] = o;
}

// ---------------------------------------------------------------------------
// Depthwise causal conv, k=4, on contiguous x_in [M][DINNER]; bf16 output.
// ---------------------------------------------------------------------------
__global__ __launch_bounds__(256) void dwconv_kernel(
    const float* __restrict__ x_in, const float* __restrict__ dwk,
    unsigned short* __restrict__ out)
{
    size_t i = (size_t)blockIdx.x * 256 + threadIdx.x;
    if (i >= (size_t)MM * DINNER) return;
    int d = (int)(i & (DINNER - 1));
    size_t bl = i >> 11;
    int l = (int)(bl & (Ll - 1));
    int b = (int)(bl >> 11);
    float acc = 0.0f;
#pragma unroll
    for (int k = 0; k < DCONV; ++k) {
        int t = l + k - (DCONV - 1);
        if (t >= 0)
            acc = fmaf(x_in[((size_t)(b * Ll + t)) * DINNER + d],
                       dwk[k * DINNER + d], acc);
    }
    out[i] = f2bf(acc);
}

// ---------------------------------------------------------------------------
// Selective scan pass 1: per-chunk local scan from h=0.
// ---------------------------------------------------------------------------
__global__ __launch_bounds__(256) void scan_pass1(
    const float* __restrict__ delta, const float* __restrict__ xc,
    const float* __restrict__ xdbl, const float* __restrict__ A_log,
    float* __restrict__ cs_a, float* __restrict__ cs_h)
{
    const int d = blockIdx.x * 256 + threadIdx.x;
    const int c = blockIdx.y;
    const int b = blockIdx.z;
    const int t0 = c * CL;

    __shared__ float sB[CL][8];
    {
        int i = threadIdx.x;
        int t = i >> 3, j = i & 7;
        sB[t][j] = xdbl[((size_t)(b * Ll + t0 + t)) * 80 + DTRANK + j];
    }
    __syncthreads();

    float An[8];
#pragma unroll
    for (int n = 0; n < 8; ++n) An[n] = -__expf(A_log[d * 8 + n]);

    float h[8], ap[8];
#pragma unroll
    for (int n = 0; n < 8; ++n) { h[n] = 0.0f; ap[n] = 1.0f; }

    const float* dptr = delta + ((size_t)(b * Ll + t0)) * DINNER + d;
    const float* xptr = xc + ((size_t)(b * Ll + t0)) * DINNER + d;

#pragma unroll 4
    for (int t = 0; t < CL; ++t) {
        float dl = dptr[(size_t)t * DINNER];
        float xv = xptr[(size_t)t * DINNER];
        float du = dl * xv;
#pragma unroll
        for (int n = 0; n < 8; ++n) {
            float dA = __expf(dl * An[n]);
            h[n] = fmaf(dA, h[n], du * sB[t][n]);
            ap[n] *= dA;
        }
    }

    size_t base = (((size_t)(b * NCH + c)) * 8) * DINNER + d;
#pragma unroll
    for (int n = 0; n < 8; ++n) {
        cs_a[base + (size_t)n * DINNER] = ap[n];
        cs_h[base + (size_t)n * DINNER] = h[n];
    }
}

// Pass 2: sequential combine; hin ALIASES cs_h (in-place) — read-before-write.
__global__ __launch_bounds__(256) void scan_pass2(
    const float* __restrict__ cs_a, const float* cs_h, float* hin)
{
    int idx = blockIdx.x * 256 + threadIdx.x;
    if (idx >= Bb * 8 * DINNER) return;
    int d = idx & (DINNER - 1);
    int n = (idx >> 11) & 7;
    int b = idx >> 14;
    float H = 0.0f;
    for (int c = 0; c < NCH; ++c) {
        size_t o = (((size_t)(b * NCH + c)) * 8 + n) * DINNER + d;
        float a = cs_a[o];
        float hh = cs_h[o];
        hin[o] = H;
        H = fmaf(a, H, hh);
    }
}

// Pass 3: replay with correct h_in; fused epilogue -> bf16 y.
__global__ __launch_bounds__(256) void scan_pass3(
    const float* __restrict__ delta, const float* __restrict__ xc,
    const float* __restrict__ xdbl, const float* __restrict__ A_log,
    const float* __restrict__ hin, const float* __restrict__ z,
    const float* __restrict__ Dvec, unsigned short* __restrict__ y_bf)
{
    const int d = blockIdx.x * 256 + threadIdx.x;
    const int c = blockIdx.y;
    const int b = blockIdx.z;
    const int t0 = c * CL;

    __shared__ float sB[CL][8];
    __shared__ float sC[CL][8];
    {
        int i = threadIdx.x;
        int t = i >> 4, j = i & 15;
        float v = xdbl[((size_t)(b * Ll + t0 + t)) * 80 + DTRANK + j];
        if (j < 8) sB[t][j] = v; else sC[t][j - 8] = v;
        t = (i + 256) >> 4; j = (i + 256) & 15;
        v = xdbl[((size_t)(b * Ll + t0 + t)) * 80 + DTRANK + j];
        if (j < 8) sB[t][j] = v; else sC[t][j - 8] = v;
    }
    __syncthreads();

    float An[8];
#pragma unroll
    for (int n = 0; n < 8; ++n) An[n] = -__expf(A_log[d * 8 + n]);

    float h[8];
    size_t hbase = (((size_t)(b * NCH + c)) * 8) * DINNER + d;
#pragma unroll
    for (int n = 0; n < 8; ++n) h[n] = hin[hbase + (size_t)n * DINNER];

    const float Dd = Dvec[d];
    const float* dptr = delta + ((size_t)(b * Ll + t0)) * DINNER + d;
    const float* xptr = xc + ((size_t)(b * Ll + t0)) * DINNER + d;
    const float* zptr = z + ((size_t)(b * Ll + t0)) * DINNER + d;
    unsigned short* yptr = y_bf + ((size_t)(b * Ll + t0)) * DINNER + d;

    for (int t = 0; t < CL; ++t) {
        float dl = dptr[(size_t)t * DINNER];
        float xv = xptr[(size_t)t * DINNER];
        float du = dl * xv;
        float yt = 0.0f;
#pragma unroll
        for (int n = 0; n < 8; ++n) {
            float dA = __expf(dl * An[n]);
            h[n] = fmaf(dA, h[n], du * sB[t][n]);
            yt = fmaf(sC[t][n], h[n], yt);
        }
        float zv = zptr[(size_t)t * DINNER];
        yptr[(size_t)t * DINNER] = f2bf((yt + xv * Dd) * silu_f(zv));
    }
}

// ---------------------------------------------------------------------------
extern "C" void kernel_launch(void* const* d_in, const int* in_sizes, int n_in,
                              void* d_out, int out_size, void* d_ws, size_t ws_size,
                              hipStream_t stream)
{
    const float* x         = (const float*)d_in[0];
    const float* W_in      = (const float*)d_in[1];
    const float* dwk       = (const float*)d_in[2];
    const float* pwk       = (const float*)d_in[3];
    const float* conv_bias = (const float*)d_in[4];
    const float* W_x       = (const float*)d_in[5];
    const float* W_dt      = (const float*)d_in[6];
    const float* b_dt      = (const float*)d_in[7];
    const float* A_log     = (const float*)d_in[8];
    const float* Dv        = (const float*)d_in[9];
    const float* W_out     = (const float*)d_in[10];
    float* out = (float*)d_out;

    // workspace map (bytes; peak 148.5 MB, <= proven 154 MB)
    char* ws = (char*)d_ws;
    float*          x_in   = (float*)(ws);                          // 32 MB, dies after dwconv
    float*          delta  = (float*)(ws);                          //  reuses x_in slot
    float*          z      = (float*)(ws + (32ull  << 20));         // 32 MB
    unsigned short* x_bf   = (unsigned short*)(ws + (64ull << 20)); //  8 MB \ die after G1;
    unsigned short* Wint   = (unsigned short*)(ws + (72ull << 20)); //  8 MB /  y_bf reuses
    unsigned short* y_bf   = (unsigned short*)(ws + (64ull << 20)); // 16 MB (over x_bf+Wint)
    unsigned short* pw_t   = (unsigned short*)(ws + (80ull << 20)); //  8 MB, dies after G2
    unsigned short* Woutt  = (unsigned short*)(ws + (80ull << 20)); //  4 MB (over pw_t)
    float*          xc     = (float*)(ws + (88ull  << 20));         // 32 MB
    unsigned short* xcp_bf = (unsigned short*)(ws + (120ull << 20));// 16 MB, dies after G2
    float*          cs_a   = (float*)(ws + (120ull << 20));         //  8 MB (over xcp_bf)
    float*          cs_h   = (float*)(ws + (128ull << 20));         //  8 MB; hin in-place
    float*          xdbl   = (float*)(ws + (136ull << 20));         //  2 MB slot
    float*          g3part = (float*)(ws + (138ull << 20));         // 10.5 MB
    float*          hin    = cs_h;

    dim3 blk(256);

    // operand prep
    cast_bf16<<<(MM * DMODEL / 4 + 255) / 256, blk, 0, stream>>>(x, x_bf, MM * DMODEL);
    transpose_cast<<<dim3((2 * DINNER) / 32, DMODEL / 32), dim3(32, 8), 0, stream>>>(
        W_in, Wint, DMODEL, 2 * DINNER);          // [1024][4096] -> [4096][1024]
    transpose_cast<<<dim3(DINNER / 32, DINNER / 32), dim3(32, 8), 0, stream>>>(
        pwk, pw_t, DINNER, DINNER);               // [2048][2048] -> [2048][2048]

    // G1a/G1b: x @ W_in split into x_in and z halves (bf16 MFMA)
    mfma_gemm<0><<<dim3(DINNER / 128, MM / 128), blk, 0, stream>>>(
        x_bf, Wint, x_in, MM, DINNER, DMODEL, DMODEL, DMODEL, DINNER, nullptr);
    mfma_gemm<0><<<dim3(DINNER / 128, MM / 128), blk, 0, stream>>>(
        x_bf, Wint + (size_t)DINNER * DMODEL, z, MM, DINNER, DMODEL,
        DMODEL, DMODEL, DINNER, nullptr);

    // depthwise causal conv (reads fp32 x_in, emits bf16)
    dwconv_kernel<<<(MM * DINNER + 255) / 256, blk, 0, stream>>>(x_in, dwk, xcp_bf);

    // G2: xc = silu(conv @ pw + conv_bias)  (bf16 MFMA, fp32 out)
    mfma_gemm<1><<<dim3(DINNER / 128, MM / 128), blk, 0, stream>>>(
        xcp_bf, pw_t, xc, MM, DINNER, DINNER, DINNER, DINNER, DINNER, conv_bias);

    // W_out transpose (pw_t slot now dead)
    transpose_cast<<<dim3(DMODEL / 32, DINNER / 32), dim3(32, 8), 0, stream>>>(
        W_out, Woutt, DINNER, DMODEL);            // [2048][1024] -> [1024][2048]

    // G3: x_dbl = xc @ W_x  (fp32 split-K, deterministic 2-pass)
    g3_splitk<<<dim3(MM / 64, G3_KCH), blk, 0, stream>>>(xc, W_x, g3part);
    g3_reduce<<<(MM * 80 / 4 + 255) / 256, blk, 0, stream>>>(g3part, xdbl);

    // G4: delta = softplus(x_dbl[:, :64] @ W_dt + b_dt)  (fp32; overwrites x_in slot)
    gemm_tiled_sp<<<dim3(DINNER / 64, MM / 64), blk, 0, stream>>>(
        xdbl, W_dt, delta, MM, DINNER, DTRANK, 80, DINNER, DINNER, b_dt);

    // selective scan, 3-pass chunked
    scan_pass1<<<dim3(DINNER / 256, NCH, Bb), blk, 0, stream>>>(
        delta, xc, xdbl, A_log, cs_a, cs_h);
    scan_pass2<<<(Bb * 8 * DINNER + 255) / 256, blk, 0, stream>>>(cs_a, cs_h, hin);
    scan_pass3<<<dim3(DINNER / 256, NCH, Bb), blk, 0, stream>>>(
        delta, xc, xdbl, A_log, hin, z, Dv, y_bf);

    // G5: out = y @ W_out  (bf16 MFMA)
    mfma_gemm<0><<<dim3(DMODEL / 128, MM / 128), blk, 0, stream>>>(
        y_bf, Woutt, out, MM, DMODEL, DINNER, DINNER, DINNER, DMODEL, nullptr);
}

// Round 5
// 419.082 us; speedup vs baseline: 3.7491x; 1.0476x over previous
//
#include <hip/hip_runtime.h>
#include <math.h>

// Problem constants
#define Bb 2
#define Ll 2048
#define DMODEL 1024
#define DINNER 2048
#define DSTATE 8
#define DTRANK 64
#define DCONV 4
#define MM (Bb*Ll)          // 4096 rows
// scan chunking
#define NCH 64
#define CL 32               // NCH*CL == Ll
// G3 split-K
#define G3_KCH 8
#define G3_KC (DINNER / G3_KCH)   // 256

typedef __attribute__((ext_vector_type(8))) short    bf16x8;
typedef __attribute__((ext_vector_type(4))) float    f32x4;

__device__ __forceinline__ float silu_f(float x) {
    return x / (1.0f + __expf(-x));
}
__device__ __forceinline__ float softplus_f(float x) {
    return fmaxf(x, 0.0f) + log1pf(__expf(-fabsf(x)));
}
__device__ __forceinline__ unsigned short f2bf(float f) {
    unsigned int u = __float_as_uint(f);
    u += 0x7fffu + ((u >> 16) & 1u);      // RNE
    return (unsigned short)(u >> 16);
}
__device__ __forceinline__ float bf2f(unsigned short u) {
    return __uint_as_float(((unsigned int)u) << 16);
}
// async 16B global->LDS (wave-uniform LDS base + lane*16 dest)
__device__ __forceinline__ void async_cp16(const unsigned short* g, unsigned short* l) {
    __builtin_amdgcn_global_load_lds(
        (const __attribute__((address_space(1))) void*)g,
        (__attribute__((address_space(3))) void*)l, 16, 0, 0);
}

// ---------------------------------------------------------------------------
// bf16 MFMA GEMM: C[M,N] = epi(A[M,K] @ Bt[N,K]^T + bias)
// 128x128 block, 4 waves, BK=32, DOUBLE-BUFFERED async staging:
//   barrier; prefetch tile k+1 -> buf^1; compute tile k from buf.
// One __syncthreads per iter (drains vmcnt for tile k, lgkm for prev reads).
// Flat LDS + 16B-slot XOR swizzle (applied global-side) -> 2-way alias only.
// EPI: 0 = none, 1 = silu(x + bias[n]). OT: float or ushort(bf16) output.
// ---------------------------------------------------------------------------
template <int EPI, typename OT>
__global__ __launch_bounds__(256) void mfma_gemm(
    const unsigned short* __restrict__ A, const unsigned short* __restrict__ Bt,
    OT* __restrict__ C, int M, int N, int K,
    int lda, int ldb, int ldc, const float* __restrict__ bias)
{
    __shared__ unsigned short As[2][128 * 32];   // 2 x 8 KB
    __shared__ unsigned short Bs[2][128 * 32];

    const int bm = blockIdx.y * 128;
    const int bn = blockIdx.x * 128;
    const int tid  = threadIdx.x;
    const int w    = tid >> 6;          // wave 0..3
    const int lane = tid & 63;
    const int wm = (w >> 1) * 64;
    const int wn = (w & 1) * 64;
    const int lr = lane & 15;
    const int lq = lane >> 4;

    // staging: wave w fills rows [w*32, w*32+32); 2 issues per operand.
    const int r1 = w * 32 + (lane >> 2);
    const int sp = lane & 3;
    const int slog = sp ^ ((r1 >> 1) & 3);   // same for r1 and r1+16
    const unsigned short* gA1 = A  + (size_t)(bm + r1) * lda + slog * 8;
    const unsigned short* gA2 = gA1 + (size_t)16 * lda;
    const unsigned short* gB1 = Bt + (size_t)(bn + r1) * ldb + slog * 8;
    const unsigned short* gB2 = gB1 + (size_t)16 * ldb;
    const int st1 = w * 1024;          // 32 rows * 32 elems per wave
    const int st2 = w * 1024 + 512;

    // fragment read offset (logical slot lq at phys slot lq^((lr>>1)&3))
    const int fsw = (lq ^ ((lr >> 1) & 3)) * 8;

    f32x4 acc[4][4];
#pragma unroll
    for (int i = 0; i < 4; ++i)
#pragma unroll
        for (int j = 0; j < 4; ++j) acc[i][j] = (f32x4){0.f, 0.f, 0.f, 0.f};

    // prologue: tile 0 -> buffer 0
    async_cp16(gA1, &As[0][st1]);
    async_cp16(gA2, &As[0][st2]);
    async_cp16(gB1, &Bs[0][st1]);
    async_cp16(gB2, &Bs[0][st2]);

    int cur = 0;
    for (int k0 = 0; k0 < K; k0 += 32, cur ^= 1) {
        __syncthreads();   // drains tile-k loads (vmcnt) + prev ds_reads (lgkm)
        const int nk = k0 + 32;
        if (nk < K) {
            const int nb = cur ^ 1;
            async_cp16(gA1 + nk, &As[nb][st1]);
            async_cp16(gA2 + nk, &As[nb][st2]);
            async_cp16(gB1 + nk, &Bs[nb][st1]);
            async_cp16(gB2 + nk, &Bs[nb][st2]);
        }

        bf16x8 a[4], b[4];
#pragma unroll
        for (int i = 0; i < 4; ++i)
            a[i] = *(const bf16x8*)&As[cur][(wm + i * 16 + lr) * 32 + fsw];
#pragma unroll
        for (int j = 0; j < 4; ++j)
            b[j] = *(const bf16x8*)&Bs[cur][(wn + j * 16 + lr) * 32 + fsw];
#pragma unroll
        for (int i = 0; i < 4; ++i)
#pragma unroll
            for (int j = 0; j < 4; ++j)
                acc[i][j] = __builtin_amdgcn_mfma_f32_16x16x32_bf16(
                    a[i], b[j], acc[i][j], 0, 0, 0);
    }

    // epilogue: C/D layout col = lane&15, row = (lane>>4)*4 + reg
#pragma unroll
    for (int i = 0; i < 4; ++i) {
        const int row0 = bm + wm + i * 16 + lq * 4;
#pragma unroll
        for (int j = 0; j < 4; ++j) {
            const int col = bn + wn + j * 16 + lr;
            float bv = (EPI == 1) ? bias[col] : 0.0f;
#pragma unroll
            for (int r = 0; r < 4; ++r) {
                float v = acc[i][j][r];
                if (EPI == 1) v = silu_f(v + bv);
                if (sizeof(OT) == 2)
                    C[(size_t)(row0 + r) * ldc + col] = (OT)f2bf(v);
                else
                    C[(size_t)(row0 + r) * ldc + col] = (OT)v;
            }
        }
    }
}

// ---------------------------------------------------------------------------
// fp32 tiled GEMM (G4 only): C = softplus(A@B + bias)
// ---------------------------------------------------------------------------
__global__ __launch_bounds__(256) void gemm_tiled_sp(
    const float* __restrict__ A, const float* __restrict__ B,
    float* __restrict__ C, int M, int N, int K,
    int lda, int ldb, int ldc, const float* __restrict__ bias)
{
    __shared__ float As[16][68];
    __shared__ float Bs[16][68];

    const int bm = blockIdx.y * 64;
    const int bn = blockIdx.x * 64;
    const int tid = threadIdx.x;
    const int tx = tid & 15;
    const int ty = tid >> 4;

    float acc[4][4];
#pragma unroll
    for (int i = 0; i < 4; ++i)
#pragma unroll
        for (int j = 0; j < 4; ++j) acc[i][j] = 0.0f;

    const int ar = tid >> 2;
    const int ac = (tid & 3) << 2;
    const int br = tid >> 4;
    const int bc = (tid & 15) << 2;

    for (int k0 = 0; k0 < K; k0 += 16) {
        float4 av = *(const float4*)&A[(size_t)(bm + ar) * lda + k0 + ac];
        float4 bv = *(const float4*)&B[(size_t)(k0 + br) * ldb + bn + bc];
        As[ac + 0][ar] = av.x;
        As[ac + 1][ar] = av.y;
        As[ac + 2][ar] = av.z;
        As[ac + 3][ar] = av.w;
        *(float4*)&Bs[br][bc] = bv;
        __syncthreads();
#pragma unroll
        for (int k = 0; k < 16; ++k) {
            float4 a4 = *(float4*)&As[k][ty * 4];
            float4 b4 = *(float4*)&Bs[k][tx * 4];
            float am[4] = {a4.x, a4.y, a4.z, a4.w};
            float bn4[4] = {b4.x, b4.y, b4.z, b4.w};
#pragma unroll
            for (int i = 0; i < 4; ++i)
#pragma unroll
                for (int j = 0; j < 4; ++j)
                    acc[i][j] = fmaf(am[i], bn4[j], acc[i][j]);
        }
        __syncthreads();
    }

    const int col = bn + tx * 4;
#pragma unroll
    for (int i = 0; i < 4; ++i) {
        int row = bm + ty * 4 + i;
        float4 v = make_float4(acc[i][0], acc[i][1], acc[i][2], acc[i][3]);
        v.x = softplus_f(v.x + bias[col + 0]);
        v.y = softplus_f(v.y + bias[col + 1]);
        v.z = softplus_f(v.z + bias[col + 2]);
        v.w = softplus_f(v.w + bias[col + 3]);
        *(float4*)&C[(size_t)row * ldc + col] = v;
    }
}

// ---------------------------------------------------------------------------
// G3 split-K: part[kc][M][80] = xc_bf[:, kc*256:(kc+1)*256] @ W_x-chunk
// xc is bf16 now. Deterministic (no atomics).
// ---------------------------------------------------------------------------
__global__ __launch_bounds__(256) void g3_splitk(
    const unsigned short* __restrict__ xc, const float* __restrict__ Wx,
    float* __restrict__ part)
{
    __shared__ float As[16][68];   // [k][row]
    __shared__ float Bs[16][85];   // [k][col]
    const int m0 = blockIdx.x * 64;
    const int kb = blockIdx.y * G3_KC;
    const int t = threadIdx.x;
    const int tr = t >> 4;
    const int tc = t & 15;

    const int arow = t >> 2;
    const int ak4  = (t & 3) * 4;
    const int bk   = t >> 4;
    const int bc   = (t & 15) * 5;

    float acc[4][5];
#pragma unroll
    for (int r = 0; r < 4; ++r)
#pragma unroll
        for (int c = 0; c < 5; ++c) acc[r][c] = 0.0f;

    for (int k0 = 0; k0 < G3_KC; k0 += 16) {
        ushort4 av = *(const ushort4*)&xc[(size_t)(m0 + arow) * DINNER + kb + k0 + ak4];
        float bv[5];
#pragma unroll
        for (int q = 0; q < 5; ++q)
            bv[q] = Wx[(size_t)(kb + k0 + bk) * 80 + bc + q];
        __syncthreads();
        As[ak4 + 0][arow] = bf2f(av.x);
        As[ak4 + 1][arow] = bf2f(av.y);
        As[ak4 + 2][arow] = bf2f(av.z);
        As[ak4 + 3][arow] = bf2f(av.w);
#pragma unroll
        for (int q = 0; q < 5; ++q) Bs[bk][bc + q] = bv[q];
        __syncthreads();
#pragma unroll
        for (int k = 0; k < 16; ++k) {
            float a[4], b[5];
#pragma unroll
            for (int r = 0; r < 4; ++r) a[r] = As[k][tr * 4 + r];
#pragma unroll
            for (int c = 0; c < 5; ++c) b[c] = Bs[k][tc * 5 + c];
#pragma unroll
            for (int r = 0; r < 4; ++r)
#pragma unroll
                for (int c = 0; c < 5; ++c)
                    acc[r][c] = fmaf(a[r], b[c], acc[r][c]);
        }
    }
#pragma unroll
    for (int r = 0; r < 4; ++r)
#pragma unroll
        for (int c = 0; c < 5; ++c)
            part[((size_t)blockIdx.y * MM + m0 + tr * 4 + r) * 80 + tc * 5 + c] = acc[r][c];
}

__global__ __launch_bounds__(256) void g3_reduce(
    const float* __restrict__ part, float* __restrict__ xdbl)
{
    int i = (blockIdx.x * 256 + threadIdx.x) * 4;
    if (i >= MM * 80) return;
    float4 s = *(const float4*)&part[i];
#pragma unroll
    for (int c = 1; c < G3_KCH; ++c) {
        float4 p = *(const float4*)&part[(size_t)c * MM * 80 + i];
        s.x += p.x; s.y += p.y; s.z += p.z; s.w += p.w;
    }
    *(float4*)&xdbl[i] = s;
}

// ---------------------------------------------------------------------------
// transpose + fp32->bf16 cast: src[R][C] fp32 -> dst[C][R] bf16
// ---------------------------------------------------------------------------
__global__ __launch_bounds__(256) void transpose_cast(
    const float* __restrict__ src, unsigned short* __restrict__ dst, int R, int C)
{
    __shared__ float tile[32][33];
    const int c0 = blockIdx.x * 32;
    const int r0 = blockIdx.y * 32;
    const int tx = threadIdx.x;
    const int ty = threadIdx.y;
#pragma unroll
    for (int i = 0; i < 32; i += 8)
        tile[ty + i][tx] = src[(size_t)(r0 + ty + i) * C + c0 + tx];
    __syncthreads();
#pragma unroll
    for (int i = 0; i < 32; i += 8)
        dst[(size_t)(c0 + ty + i) * R + r0 + tx] = f2bf(tile[tx][ty + i]);
}

__global__ __launch_bounds__(256) void cast_bf16(
    const float* __restrict__ src, unsigned short* __restrict__ dst, int n)
{
    int i = (blockIdx.x * 256 + threadIdx.x) * 4;
    if (i >= n) return;
    float4 v = *(const float4*)&src[i];
    ushort4 o;
    o.x = f2bf(v.x); o.y = f2bf(v.y); o.z = f2bf(v.z); o.w = f2bf(v.w);
    *(ushort4*)&dst[i] = o;
}

// ---------------------------------------------------------------------------
// Depthwise causal conv on the x_in half of xz [M][2*DINNER]; bf16 output.
// ---------------------------------------------------------------------------
__global__ __launch_bounds__(256) void dwconv_kernel(
    const float* __restrict__ xz, const float* __restrict__ dwk,
    unsigned short* __restrict__ out)
{
    size_t i = (size_t)blockIdx.x * 256 + threadIdx.x;
    if (i >= (size_t)MM * DINNER) return;
    int d = (int)(i & (DINNER - 1));
    size_t bl = i >> 11;
    int l = (int)(bl & (Ll - 1));
    int b = (int)(bl >> 11);
    float acc = 0.0f;
#pragma unroll
    for (int k = 0; k < DCONV; ++k) {
        int t = l + k - (DCONV - 1);
        if (t >= 0)
            acc = fmaf(xz[((size_t)(b * Ll + t)) * (2 * DINNER) + d],
                       dwk[k * DINNER + d], acc);
    }
    out[i] = f2bf(acc);
}

// ---------------------------------------------------------------------------
// Selective scan pass 1: per-chunk local scan from h=0. xc is bf16.
// ---------------------------------------------------------------------------
__global__ __launch_bounds__(256) void scan_pass1(
    const float* __restrict__ delta, const unsigned short* __restrict__ xc,
    const float* __restrict__ xdbl, const float* __restrict__ A_log,
    float* __restrict__ cs_a, float* __restrict__ cs_h)
{
    const int d = blockIdx.x * 256 + threadIdx.x;
    const int c = blockIdx.y;
    const int b = blockIdx.z;
    const int t0 = c * CL;

    __shared__ float sB[CL][8];
    {
        int i = threadIdx.x;
        int t = i >> 3, j = i & 7;
        sB[t][j] = xdbl[((size_t)(b * Ll + t0 + t)) * 80 + DTRANK + j];
    }
    __syncthreads();

    float An[8];
#pragma unroll
    for (int n = 0; n < 8; ++n) An[n] = -__expf(A_log[d * 8 + n]);

    float h[8], ap[8];
#pragma unroll
    for (int n = 0; n < 8; ++n) { h[n] = 0.0f; ap[n] = 1.0f; }

    const float* dptr = delta + ((size_t)(b * Ll + t0)) * DINNER + d;
    const unsigned short* xptr = xc + ((size_t)(b * Ll + t0)) * DINNER + d;

#pragma unroll 4
    for (int t = 0; t < CL; ++t) {
        float dl = dptr[(size_t)t * DINNER];
        float xv = bf2f(xptr[(size_t)t * DINNER]);
        float du = dl * xv;
#pragma unroll
        for (int n = 0; n < 8; ++n) {
            float dA = __expf(dl * An[n]);
            h[n] = fmaf(dA, h[n], du * sB[t][n]);
            ap[n] *= dA;
        }
    }

    size_t base = (((size_t)(b * NCH + c)) * 8) * DINNER + d;
#pragma unroll
    for (int n = 0; n < 8; ++n) {
        cs_a[base + (size_t)n * DINNER] = ap[n];
        cs_h[base + (size_t)n * DINNER] = h[n];
    }
}

// Pass 2: sequential combine; hin ALIASES cs_h (in-place) — read-before-write.
__global__ __launch_bounds__(256) void scan_pass2(
    const float* __restrict__ cs_a, const float* cs_h, float* hin)
{
    int idx = blockIdx.x * 256 + threadIdx.x;
    if (idx >= Bb * 8 * DINNER) return;
    int d = idx & (DINNER - 1);
    int n = (idx >> 11) & 7;
    int b = idx >> 14;
    float H = 0.0f;
    for (int c = 0; c < NCH; ++c) {
        size_t o = (((size_t)(b * NCH + c)) * 8 + n) * DINNER + d;
        float a = cs_a[o];
        float hh = cs_h[o];
        hin[o] = H;
        H = fmaf(a, H, hh);
    }
}

// Pass 3: replay with correct h_in; fused epilogue -> bf16 y.
// z is the second half of xz (stride 2*DINNER).
__global__ __launch_bounds__(256) void scan_pass3(
    const float* __restrict__ delta, const unsigned short* __restrict__ xc,
    const float* __restrict__ xdbl, const float* __restrict__ A_log,
    const float* __restrict__ hin, const float* __restrict__ xz,
    const float* __restrict__ Dvec, unsigned short* __restrict__ y_bf)
{
    const int d = blockIdx.x * 256 + threadIdx.x;
    const int c = blockIdx.y;
    const int b = blockIdx.z;
    const int t0 = c * CL;

    __shared__ float sB[CL][8];
    __shared__ float sC[CL][8];
    {
        int i = threadIdx.x;
        int t = i >> 4, j = i & 15;
        float v = xdbl[((size_t)(b * Ll + t0 + t)) * 80 + DTRANK + j];
        if (j < 8) sB[t][j] = v; else sC[t][j - 8] = v;
        t = (i + 256) >> 4; j = (i + 256) & 15;
        v = xdbl[((size_t)(b * Ll + t0 + t)) * 80 + DTRANK + j];
        if (j < 8) sB[t][j] = v; else sC[t][j - 8] = v;
    }
    __syncthreads();

    float An[8];
#pragma unroll
    for (int n = 0; n < 8; ++n) An[n] = -__expf(A_log[d * 8 + n]);

    float h[8];
    size_t hbase = (((size_t)(b * NCH + c)) * 8) * DINNER + d;
#pragma unroll
    for (int n = 0; n < 8; ++n) h[n] = hin[hbase + (size_t)n * DINNER];

    const float Dd = Dvec[d];
    const float* dptr = delta + ((size_t)(b * Ll + t0)) * DINNER + d;
    const unsigned short* xptr = xc + ((size_t)(b * Ll + t0)) * DINNER + d;
    const float* zptr = xz + ((size_t)(b * Ll + t0)) * (2 * DINNER) + DINNER + d;
    unsigned short* yptr = y_bf + ((size_t)(b * Ll + t0)) * DINNER + d;

    for (int t = 0; t < CL; ++t) {
        float dl = dptr[(size_t)t * DINNER];
        float xv = bf2f(xptr[(size_t)t * DINNER]);
        float du = dl * xv;
        float yt = 0.0f;
#pragma unroll
        for (int n = 0; n < 8; ++n) {
            float dA = __expf(dl * An[n]);
            h[n] = fmaf(dA, h[n], du * sB[t][n]);
            yt = fmaf(sC[t][n], h[n], yt);
        }
        float zv = zptr[(size_t)t * (2 * DINNER)];
        yptr[(size_t)t * DINNER] = f2bf((yt + xv * Dd) * silu_f(zv));
    }
}

// ---------------------------------------------------------------------------
extern "C" void kernel_launch(void* const* d_in, const int* in_sizes, int n_in,
                              void* d_out, int out_size, void* d_ws, size_t ws_size,
                              hipStream_t stream)
{
    const float* x         = (const float*)d_in[0];
    const float* W_in      = (const float*)d_in[1];
    const float* dwk       = (const float*)d_in[2];
    const float* pwk       = (const float*)d_in[3];
    const float* conv_bias = (const float*)d_in[4];
    const float* W_x       = (const float*)d_in[5];
    const float* W_dt      = (const float*)d_in[6];
    const float* b_dt      = (const float*)d_in[7];
    const float* A_log     = (const float*)d_in[8];
    const float* Dv        = (const float*)d_in[9];
    const float* W_out     = (const float*)d_in[10];
    float* out = (float*)d_out;

    // workspace map (MiB offsets; peak 152 MiB <= proven 154)
    // timeline: prep -> G1 -> conv -> G2 -> WoutT -> g3 -> g3red -> G4 -> p1 -> p2 -> p3 -> G5
    char* ws = (char*)d_ws;
    float*          xz     = (float*)(ws);                           // [0,64) G1..p3
    unsigned short* x_bf   = (unsigned short*)(ws + (64ull  << 20)); // [64,72) prep..G1
    unsigned short* Wint   = (unsigned short*)(ws + (72ull  << 20)); // [72,80) prep..G1
    float*          g3part = (float*)(ws + (64ull  << 20));          // [64,74) g3..g3red
    float*          delta  = (float*)(ws + (64ull  << 20));          // [64,96) G4..p3
    unsigned short* pw_t   = (unsigned short*)(ws + (96ull  << 20)); // [96,104) prep..G2
    float*          cs_a   = (float*)(ws + (96ull  << 20));          // [96,104) p1..p2
    unsigned short* xcp_bf = (unsigned short*)(ws + (104ull << 20)); // [104,120) conv..G2
    float*          cs_h   = (float*)(ws + (104ull << 20));          // [104,112) p1..p3
    unsigned short* Woutt  = (unsigned short*)(ws + (112ull << 20)); // [112,116) WoutT..G5
    float*          xdbl   = (float*)(ws + (116ull << 20));          // [116,117.25) g3red..p3
    unsigned short* xc_bf  = (unsigned short*)(ws + (120ull << 20)); // [120,136) G2..p3
    unsigned short* y_bf   = (unsigned short*)(ws + (136ull << 20)); // [136,152) p3..G5
    float*          hin    = cs_h;   // in-place

    dim3 blk(256);

    // operand prep
    cast_bf16<<<(MM * DMODEL / 4 + 255) / 256, blk, 0, stream>>>(x, x_bf, MM * DMODEL);
    transpose_cast<<<dim3((2 * DINNER) / 32, DMODEL / 32), dim3(32, 8), 0, stream>>>(
        W_in, Wint, DMODEL, 2 * DINNER);          // [1024][4096] -> [4096][1024]
    transpose_cast<<<dim3(DINNER / 32, DINNER / 32), dim3(32, 8), 0, stream>>>(
        pwk, pw_t, DINNER, DINNER);               // [2048][2048] -> [2048][2048]

    // G1: xz = x @ W_in  (single N=4096 launch, 1024 blocks)
    mfma_gemm<0, float><<<dim3((2 * DINNER) / 128, MM / 128), blk, 0, stream>>>(
        x_bf, Wint, xz, MM, 2 * DINNER, DMODEL, DMODEL, DMODEL, 2 * DINNER, nullptr);

    // depthwise causal conv on x_in half of xz (emits bf16)
    dwconv_kernel<<<(MM * DINNER + 255) / 256, blk, 0, stream>>>(xz, dwk, xcp_bf);

    // G2: xc = silu(conv @ pw + conv_bias)  -> bf16 output
    mfma_gemm<1, unsigned short><<<dim3(DINNER / 128, MM / 128), blk, 0, stream>>>(
        xcp_bf, pw_t, xc_bf, MM, DINNER, DINNER, DINNER, DINNER, DINNER, conv_bias);

    // W_out transpose (xcp/pw_t regions now dead where needed)
    transpose_cast<<<dim3(DMODEL / 32, DINNER / 32), dim3(32, 8), 0, stream>>>(
        W_out, Woutt, DINNER, DMODEL);            // [2048][1024] -> [1024][2048]

    // G3: x_dbl = xc @ W_x  (split-K fp32 accumulate from bf16 xc)
    g3_splitk<<<dim3(MM / 64, G3_KCH), blk, 0, stream>>>(xc_bf, W_x, g3part);
    g3_reduce<<<(MM * 80 / 4 + 255) / 256, blk, 0, stream>>>(g3part, xdbl);

    // G4: delta = softplus(x_dbl[:, :64] @ W_dt + b_dt)  (fp32)
    gemm_tiled_sp<<<dim3(DINNER / 64, MM / 64), blk, 0, stream>>>(
        xdbl, W_dt, delta, MM, DINNER, DTRANK, 80, DINNER, DINNER, b_dt);

    // selective scan, 3-pass chunked
    scan_pass1<<<dim3(DINNER / 256, NCH, Bb), blk, 0, stream>>>(
        delta, xc_bf, xdbl, A_log, cs_a, cs_h);
    scan_pass2<<<(Bb * 8 * DINNER + 255) / 256, blk, 0, stream>>>(cs_a, cs_h, hin);
    scan_pass3<<<dim3(DINNER / 256, NCH, Bb), blk, 0, stream>>>(
        delta, xc_bf, xdbl, A_log, hin, xz, Dv, y_bf);

    // G5: out = y @ W_out
    mfma_gemm<0, float><<<dim3(DMODEL / 128, MM / 128), blk, 0, stream>>>(
        y_bf, Woutt, out, MM, DMODEL, DINNER, DINNER, DINNER, DMODEL, nullptr);
}

// Round 6
// 397.935 us; speedup vs baseline: 3.9483x; 1.0531x over previous
//
#include <hip/hip_runtime.h>
#include <math.h>

// Problem constants
#define Bb 2
#define Ll 2048
#define DMODEL 1024
#define DINNER 2048
#define DSTATE 8
#define DTRANK 64
#define DCONV 4
#define MM (Bb*Ll)          // 4096 rows
// scan chunking
#define NCH 64
#define CL 32               // NCH*CL == Ll
// G3 split-K
#define G3_KCH 8
#define G3_KC (DINNER / G3_KCH)   // 256

typedef __attribute__((ext_vector_type(8))) short    bf16x8;
typedef __attribute__((ext_vector_type(4))) float    f32x4;

__device__ __forceinline__ float silu_f(float x) {
    return x / (1.0f + __expf(-x));
}
__device__ __forceinline__ float softplus_f(float x) {
    return fmaxf(x, 0.0f) + log1pf(__expf(-fabsf(x)));
}
__device__ __forceinline__ unsigned short f2bf(float f) {
    unsigned int u = __float_as_uint(f);
    u += 0x7fffu + ((u >> 16) & 1u);      // RNE
    return (unsigned short)(u >> 16);
}
__device__ __forceinline__ float bf2f(unsigned short u) {
    return __uint_as_float(((unsigned int)u) << 16);
}
// async 16B global->LDS (wave-uniform LDS base + lane*16 dest)
__device__ __forceinline__ void async_cp16(const unsigned short* g, unsigned short* l) {
    __builtin_amdgcn_global_load_lds(
        (const __attribute__((address_space(1))) void*)g,
        (__attribute__((address_space(3))) void*)l, 16, 0, 0);
}

// ---------------------------------------------------------------------------
// bf16 MFMA GEMM, 512 threads / 8 waves per block (16 waves/CU at 2 blk/CU).
// C[M,N] = epi(A[M,K] @ Bt[N,K]^T + bias). 128x128 tile, BK=32,
// double-buffered async staging, flat LDS + XOR slot swizzle (global-side).
// Wave tile 64x32: acc 4x2, 8 MFMA + 6 ds_read_b128 per K-iter.
// Split output: col < nsplit -> C, else C2[col-nsplit] (block-uniform branch).
// Split-K: blockIdx.z offsets A/Bt by z*K and C by z*czstride.
// EPI: 0 none, 1 silu(x + bias[n]). OT: float or ushort (bf16).
// ---------------------------------------------------------------------------
template <int EPI, typename OT>
__global__ __launch_bounds__(512, 4) void mfma_gemm(
    const unsigned short* __restrict__ A, const unsigned short* __restrict__ Bt,
    OT* __restrict__ C, OT* __restrict__ C2, int nsplit, size_t czstride,
    int M, int N, int K, int lda, int ldb, int ldc,
    const float* __restrict__ bias)
{
    __shared__ unsigned short As[2][128 * 32];   // 2 x 8 KB
    __shared__ unsigned short Bs[2][128 * 32];

    const int bm = blockIdx.y * 128;
    const int bn = blockIdx.x * 128;
    const int tid  = threadIdx.x;
    const int w    = tid >> 6;          // wave 0..7
    const int lane = tid & 63;
    const int wm = (w >> 2) * 64;       // 2 m-halves
    const int wn = (w & 3) * 32;        // 4 n-quarters
    const int lr = lane & 15;
    const int lq = lane >> 4;

    // split-K offsets
    const size_t kz = (size_t)blockIdx.z * K;
    A  += kz;
    Bt += kz;
    C  += (size_t)blockIdx.z * czstride;

    // staging: thread t covers row t>>2 (0..127), 16B slot t&3; one issue for
    // A rows, one for B rows. LDS dest = tid*8 shorts = wave base + lane*16B.
    const int row = tid >> 2;
    const int sp  = tid & 3;
    const int slog = sp ^ ((row >> 1) & 3);
    const unsigned short* gA = A  + (size_t)(bm + row) * lda + slog * 8;
    const unsigned short* gB = Bt + (size_t)(bn + row) * ldb + slog * 8;
    const int st = tid * 8;

    // fragment read offset (logical slot lq at phys slot lq^((lr>>1)&3))
    const int fsw = (lq ^ ((lr >> 1) & 3)) * 8;

    f32x4 acc[4][2];
#pragma unroll
    for (int i = 0; i < 4; ++i)
#pragma unroll
        for (int j = 0; j < 2; ++j) acc[i][j] = (f32x4){0.f, 0.f, 0.f, 0.f};

    // prologue: tile 0 -> buffer 0
    async_cp16(gA, &As[0][st]);
    async_cp16(gB, &Bs[0][st]);

    int cur = 0;
    for (int k0 = 0; k0 < K; k0 += 32, cur ^= 1) {
        __syncthreads();   // drains tile-k loads (vmcnt) + prev ds_reads (lgkm)
        const int nk = k0 + 32;
        if (nk < K) {
            const int nb = cur ^ 1;
            async_cp16(gA + nk, &As[nb][st]);
            async_cp16(gB + nk, &Bs[nb][st]);
        }

        bf16x8 a[4], b[2];
#pragma unroll
        for (int i = 0; i < 4; ++i)
            a[i] = *(const bf16x8*)&As[cur][(wm + i * 16 + lr) * 32 + fsw];
#pragma unroll
        for (int j = 0; j < 2; ++j)
            b[j] = *(const bf16x8*)&Bs[cur][(wn + j * 16 + lr) * 32 + fsw];
#pragma unroll
        for (int i = 0; i < 4; ++i)
#pragma unroll
            for (int j = 0; j < 2; ++j)
                acc[i][j] = __builtin_amdgcn_mfma_f32_16x16x32_bf16(
                    a[i], b[j], acc[i][j], 0, 0, 0);
    }

    // epilogue: C/D layout col = lane&15, row = (lane>>4)*4 + reg
#pragma unroll
    for (int i = 0; i < 4; ++i) {
        const int row0 = bm + wm + i * 16 + lq * 4;
#pragma unroll
        for (int j = 0; j < 2; ++j) {
            const int col = bn + wn + j * 16 + lr;
            OT* Cb; int colb;
            if (col < nsplit) { Cb = C; colb = col; }
            else              { Cb = C2; colb = col - nsplit; }
            float bv = (EPI == 1) ? bias[col] : 0.0f;
#pragma unroll
            for (int r = 0; r < 4; ++r) {
                float v = acc[i][j][r];
                if (EPI == 1) v = silu_f(v + bv);
                if (sizeof(OT) == 2)
                    Cb[(size_t)(row0 + r) * ldc + colb] = (OT)f2bf(v);
                else
                    Cb[(size_t)(row0 + r) * ldc + colb] = (OT)v;
            }
        }
    }
}

// fp32 add of two split-K partials -> out
__global__ __launch_bounds__(256) void g5_reduce(
    const float* __restrict__ part, float* __restrict__ out, int n)
{
    int i = (blockIdx.x * 256 + threadIdx.x) * 4;
    if (i >= n) return;
    float4 a = *(const float4*)&part[i];
    float4 b = *(const float4*)&part[(size_t)n + i];
    a.x += b.x; a.y += b.y; a.z += b.z; a.w += b.w;
    *(float4*)&out[i] = a;
}

// ---------------------------------------------------------------------------
// fp32 tiled GEMM (G4 only): C = softplus(A@B + bias)
// ---------------------------------------------------------------------------
__global__ __launch_bounds__(256) void gemm_tiled_sp(
    const float* __restrict__ A, const float* __restrict__ B,
    float* __restrict__ C, int M, int N, int K,
    int lda, int ldb, int ldc, const float* __restrict__ bias)
{
    __shared__ float As[16][68];
    __shared__ float Bs[16][68];

    const int bm = blockIdx.y * 64;
    const int bn = blockIdx.x * 64;
    const int tid = threadIdx.x;
    const int tx = tid & 15;
    const int ty = tid >> 4;

    float acc[4][4];
#pragma unroll
    for (int i = 0; i < 4; ++i)
#pragma unroll
        for (int j = 0; j < 4; ++j) acc[i][j] = 0.0f;

    const int ar = tid >> 2;
    const int ac = (tid & 3) << 2;
    const int br = tid >> 4;
    const int bc = (tid & 15) << 2;

    for (int k0 = 0; k0 < K; k0 += 16) {
        float4 av = *(const float4*)&A[(size_t)(bm + ar) * lda + k0 + ac];
        float4 bv = *(const float4*)&B[(size_t)(k0 + br) * ldb + bn + bc];
        As[ac + 0][ar] = av.x;
        As[ac + 1][ar] = av.y;
        As[ac + 2][ar] = av.z;
        As[ac + 3][ar] = av.w;
        *(float4*)&Bs[br][bc] = bv;
        __syncthreads();
#pragma unroll
        for (int k = 0; k < 16; ++k) {
            float4 a4 = *(float4*)&As[k][ty * 4];
            float4 b4 = *(float4*)&Bs[k][tx * 4];
            float am[4] = {a4.x, a4.y, a4.z, a4.w};
            float bn4[4] = {b4.x, b4.y, b4.z, b4.w};
#pragma unroll
            for (int i = 0; i < 4; ++i)
#pragma unroll
                for (int j = 0; j < 4; ++j)
                    acc[i][j] = fmaf(am[i], bn4[j], acc[i][j]);
        }
        __syncthreads();
    }

    const int col = bn + tx * 4;
#pragma unroll
    for (int i = 0; i < 4; ++i) {
        int row = bm + ty * 4 + i;
        float4 v = make_float4(acc[i][0], acc[i][1], acc[i][2], acc[i][3]);
        v.x = softplus_f(v.x + bias[col + 0]);
        v.y = softplus_f(v.y + bias[col + 1]);
        v.z = softplus_f(v.z + bias[col + 2]);
        v.w = softplus_f(v.w + bias[col + 3]);
        *(float4*)&C[(size_t)row * ldc + col] = v;
    }
}

// ---------------------------------------------------------------------------
// G3 split-K: part[kc][M][80] = xc_bf[:, kc*256:(kc+1)*256] @ W_x-chunk
// ---------------------------------------------------------------------------
__global__ __launch_bounds__(256) void g3_splitk(
    const unsigned short* __restrict__ xc, const float* __restrict__ Wx,
    float* __restrict__ part)
{
    __shared__ float As[16][68];   // [k][row]
    __shared__ float Bs[16][85];   // [k][col]
    const int m0 = blockIdx.x * 64;
    const int kb = blockIdx.y * G3_KC;
    const int t = threadIdx.x;
    const int tr = t >> 4;
    const int tc = t & 15;

    const int arow = t >> 2;
    const int ak4  = (t & 3) * 4;
    const int bk   = t >> 4;
    const int bc   = (t & 15) * 5;

    float acc[4][5];
#pragma unroll
    for (int r = 0; r < 4; ++r)
#pragma unroll
        for (int c = 0; c < 5; ++c) acc[r][c] = 0.0f;

    for (int k0 = 0; k0 < G3_KC; k0 += 16) {
        ushort4 av = *(const ushort4*)&xc[(size_t)(m0 + arow) * DINNER + kb + k0 + ak4];
        float bv[5];
#pragma unroll
        for (int q = 0; q < 5; ++q)
            bv[q] = Wx[(size_t)(kb + k0 + bk) * 80 + bc + q];
        __syncthreads();
        As[ak4 + 0][arow] = bf2f(av.x);
        As[ak4 + 1][arow] = bf2f(av.y);
        As[ak4 + 2][arow] = bf2f(av.z);
        As[ak4 + 3][arow] = bf2f(av.w);
#pragma unroll
        for (int q = 0; q < 5; ++q) Bs[bk][bc + q] = bv[q];
        __syncthreads();
#pragma unroll
        for (int k = 0; k < 16; ++k) {
            float a[4], b[5];
#pragma unroll
            for (int r = 0; r < 4; ++r) a[r] = As[k][tr * 4 + r];
#pragma unroll
            for (int c = 0; c < 5; ++c) b[c] = Bs[k][tc * 5 + c];
#pragma unroll
            for (int r = 0; r < 4; ++r)
#pragma unroll
                for (int c = 0; c < 5; ++c)
                    acc[r][c] = fmaf(a[r], b[c], acc[r][c]);
        }
    }
#pragma unroll
    for (int r = 0; r < 4; ++r)
#pragma unroll
        for (int c = 0; c < 5; ++c)
            part[((size_t)blockIdx.y * MM + m0 + tr * 4 + r) * 80 + tc * 5 + c] = acc[r][c];
}

__global__ __launch_bounds__(256) void g3_reduce(
    const float* __restrict__ part, float* __restrict__ xdbl)
{
    int i = (blockIdx.x * 256 + threadIdx.x) * 4;
    if (i >= MM * 80) return;
    float4 s = *(const float4*)&part[i];
#pragma unroll
    for (int c = 1; c < G3_KCH; ++c) {
        float4 p = *(const float4*)&part[(size_t)c * MM * 80 + i];
        s.x += p.x; s.y += p.y; s.z += p.z; s.w += p.w;
    }
    *(float4*)&xdbl[i] = s;
}

// ---------------------------------------------------------------------------
// transpose + fp32->bf16 cast: src[R][C] fp32 -> dst[C][R] bf16
// ---------------------------------------------------------------------------
__global__ __launch_bounds__(256) void transpose_cast(
    const float* __restrict__ src, unsigned short* __restrict__ dst, int R, int C)
{
    __shared__ float tile[32][33];
    const int c0 = blockIdx.x * 32;
    const int r0 = blockIdx.y * 32;
    const int tx = threadIdx.x;
    const int ty = threadIdx.y;
#pragma unroll
    for (int i = 0; i < 32; i += 8)
        tile[ty + i][tx] = src[(size_t)(r0 + ty + i) * C + c0 + tx];
    __syncthreads();
#pragma unroll
    for (int i = 0; i < 32; i += 8)
        dst[(size_t)(c0 + ty + i) * R + r0 + tx] = f2bf(tile[tx][ty + i]);
}

__global__ __launch_bounds__(256) void cast_bf16(
    const float* __restrict__ src, unsigned short* __restrict__ dst, int n)
{
    int i = (blockIdx.x * 256 + threadIdx.x) * 4;
    if (i >= n) return;
    float4 v = *(const float4*)&src[i];
    ushort4 o;
    o.x = f2bf(v.x); o.y = f2bf(v.y); o.z = f2bf(v.z); o.w = f2bf(v.w);
    *(ushort4*)&dst[i] = o;
}

// ---------------------------------------------------------------------------
// Depthwise causal conv on dense bf16 x_in [M][DINNER]; bf16 out; x4 vector.
// ---------------------------------------------------------------------------
__global__ __launch_bounds__(256) void dwconv_kernel(
    const unsigned short* __restrict__ x_in, const float* __restrict__ dwk,
    unsigned short* __restrict__ out)
{
    int i4 = blockIdx.x * 256 + threadIdx.x;
    if (i4 >= MM * DINNER / 4) return;
    int d = (i4 * 4) & (DINNER - 1);
    int bl = (i4 * 4) >> 11;
    int l = bl & (Ll - 1);
    int b = bl >> 11;
    float a0 = 0.f, a1 = 0.f, a2 = 0.f, a3 = 0.f;
#pragma unroll
    for (int k = 0; k < DCONV; ++k) {
        int t = l + k - (DCONV - 1);
        if (t >= 0) {
            ushort4 xv = *(const ushort4*)&x_in[(size_t)(b * Ll + t) * DINNER + d];
            float4 wv = *(const float4*)&dwk[k * DINNER + d];
            a0 = fmaf(bf2f(xv.x), wv.x, a0);
            a1 = fmaf(bf2f(xv.y), wv.y, a1);
            a2 = fmaf(bf2f(xv.z), wv.z, a2);
            a3 = fmaf(bf2f(xv.w), wv.w, a3);
        }
    }
    ushort4 o;
    o.x = f2bf(a0); o.y = f2bf(a1); o.z = f2bf(a2); o.w = f2bf(a3);
    *(ushort4*)&out[i4 * 4] = o;
}

// ---------------------------------------------------------------------------
// Selective scan pass 1: per-chunk local scan from h=0. xc is bf16.
// ---------------------------------------------------------------------------
__global__ __launch_bounds__(256) void scan_pass1(
    const float* __restrict__ delta, const unsigned short* __restrict__ xc,
    const float* __restrict__ xdbl, const float* __restrict__ A_log,
    float* __restrict__ cs_a, float* __restrict__ cs_h)
{
    const int d = blockIdx.x * 256 + threadIdx.x;
    const int c = blockIdx.y;
    const int b = blockIdx.z;
    const int t0 = c * CL;

    __shared__ float sB[CL][8];
    {
        int i = threadIdx.x;
        int t = i >> 3, j = i & 7;
        sB[t][j] = xdbl[((size_t)(b * Ll + t0 + t)) * 80 + DTRANK + j];
    }
    __syncthreads();

    float An[8];
#pragma unroll
    for (int n = 0; n < 8; ++n) An[n] = -__expf(A_log[d * 8 + n]);

    float h[8], ap[8];
#pragma unroll
    for (int n = 0; n < 8; ++n) { h[n] = 0.0f; ap[n] = 1.0f; }

    const float* dptr = delta + ((size_t)(b * Ll + t0)) * DINNER + d;
    const unsigned short* xptr = xc + ((size_t)(b * Ll + t0)) * DINNER + d;

#pragma unroll 4
    for (int t = 0; t < CL; ++t) {
        float dl = dptr[(size_t)t * DINNER];
        float xv = bf2f(xptr[(size_t)t * DINNER]);
        float du = dl * xv;
#pragma unroll
        for (int n = 0; n < 8; ++n) {
            float dA = __expf(dl * An[n]);
            h[n] = fmaf(dA, h[n], du * sB[t][n]);
            ap[n] *= dA;
        }
    }

    size_t base = (((size_t)(b * NCH + c)) * 8) * DINNER + d;
#pragma unroll
    for (int n = 0; n < 8; ++n) {
        cs_a[base + (size_t)n * DINNER] = ap[n];
        cs_h[base + (size_t)n * DINNER] = h[n];
    }
}

// Pass 2: sequential combine; hin ALIASES cs_h (in-place) — read-before-write.
__global__ __launch_bounds__(256) void scan_pass2(
    const float* __restrict__ cs_a, const float* cs_h, float* hin)
{
    int idx = blockIdx.x * 256 + threadIdx.x;
    if (idx >= Bb * 8 * DINNER) return;
    int d = idx & (DINNER - 1);
    int n = (idx >> 11) & 7;
    int b = idx >> 14;
    float H = 0.0f;
    for (int c = 0; c < NCH; ++c) {
        size_t o = (((size_t)(b * NCH + c)) * 8 + n) * DINNER + d;
        float a = cs_a[o];
        float hh = cs_h[o];
        hin[o] = H;
        H = fmaf(a, H, hh);
    }
}

// Pass 3: replay with correct h_in; fused epilogue -> bf16 y. z dense bf16.
__global__ __launch_bounds__(256) void scan_pass3(
    const float* __restrict__ delta, const unsigned short* __restrict__ xc,
    const float* __restrict__ xdbl, const float* __restrict__ A_log,
    const float* __restrict__ hin, const unsigned short* __restrict__ z,
    const float* __restrict__ Dvec, unsigned short* __restrict__ y_bf)
{
    const int d = blockIdx.x * 256 + threadIdx.x;
    const int c = blockIdx.y;
    const int b = blockIdx.z;
    const int t0 = c * CL;

    __shared__ float sB[CL][8];
    __shared__ float sC[CL][8];
    {
        int i = threadIdx.x;
        int t = i >> 4, j = i & 15;
        float v = xdbl[((size_t)(b * Ll + t0 + t)) * 80 + DTRANK + j];
        if (j < 8) sB[t][j] = v; else sC[t][j - 8] = v;
        t = (i + 256) >> 4; j = (i + 256) & 15;
        v = xdbl[((size_t)(b * Ll + t0 + t)) * 80 + DTRANK + j];
        if (j < 8) sB[t][j] = v; else sC[t][j - 8] = v;
    }
    __syncthreads();

    float An[8];
#pragma unroll
    for (int n = 0; n < 8; ++n) An[n] = -__expf(A_log[d * 8 + n]);

    float h[8];
    size_t hbase = (((size_t)(b * NCH + c)) * 8) * DINNER + d;
#pragma unroll
    for (int n = 0; n < 8; ++n) h[n] = hin[hbase + (size_t)n * DINNER];

    const float Dd = Dvec[d];
    const float* dptr = delta + ((size_t)(b * Ll + t0)) * DINNER + d;
    const unsigned short* xptr = xc + ((size_t)(b * Ll + t0)) * DINNER + d;
    const unsigned short* zptr = z + ((size_t)(b * Ll + t0)) * DINNER + d;
    unsigned short* yptr = y_bf + ((size_t)(b * Ll + t0)) * DINNER + d;

    for (int t = 0; t < CL; ++t) {
        float dl = dptr[(size_t)t * DINNER];
        float xv = bf2f(xptr[(size_t)t * DINNER]);
        float du = dl * xv;
        float yt = 0.0f;
#pragma unroll
        for (int n = 0; n < 8; ++n) {
            float dA = __expf(dl * An[n]);
            h[n] = fmaf(dA, h[n], du * sB[t][n]);
            yt = fmaf(sC[t][n], h[n], yt);
        }
        float zv = bf2f(zptr[(size_t)t * DINNER]);
        yptr[(size_t)t * DINNER] = f2bf((yt + xv * Dd) * silu_f(zv));
    }
}

// ---------------------------------------------------------------------------
extern "C" void kernel_launch(void* const* d_in, const int* in_sizes, int n_in,
                              void* d_out, int out_size, void* d_ws, size_t ws_size,
                              hipStream_t stream)
{
    const float* x         = (const float*)d_in[0];
    const float* W_in      = (const float*)d_in[1];
    const float* dwk       = (const float*)d_in[2];
    const float* pwk       = (const float*)d_in[3];
    const float* conv_bias = (const float*)d_in[4];
    const float* W_x       = (const float*)d_in[5];
    const float* W_dt      = (const float*)d_in[6];
    const float* b_dt      = (const float*)d_in[7];
    const float* A_log     = (const float*)d_in[8];
    const float* Dv        = (const float*)d_in[9];
    const float* W_out     = (const float*)d_in[10];
    float* out = (float*)d_out;

    // workspace map (MiB offsets; peak 152 MiB <= proven 154)
    char* ws = (char*)d_ws;
    unsigned short* x_in_bf = (unsigned short*)(ws);                  // [0,16)   G1..conv
    unsigned short* z_bf    = (unsigned short*)(ws + (16ull << 20));  // [16,32)  G1..p3
    float*          delta   = (float*)(ws + (32ull << 20));           // [32,64)  G4..p3
    float*          g5part  = (float*)(ws + (32ull << 20));           // [32,64)  G5 (after p3)
    unsigned short* x_bf    = (unsigned short*)(ws + (64ull << 20));  // [64,72)  prep..G1
    unsigned short* y_bf    = (unsigned short*)(ws + (64ull << 20));  // [64,72)  p3..G5
    unsigned short* Wint    = (unsigned short*)(ws + (72ull << 20));  // [72,80)  prep..G1
    unsigned short* pw_t    = (unsigned short*)(ws + (80ull << 20));  // [80,88)  prep..G2
    unsigned short* xcp_bf  = (unsigned short*)(ws + (88ull << 20));  // [88,104) conv..G2
    unsigned short* xc_bf   = (unsigned short*)(ws + (104ull << 20)); // [104,120) G2..p3
    unsigned short* Woutt   = (unsigned short*)(ws + (120ull << 20)); // [120,124) prep..G5
    float*          xdbl    = (float*)(ws + (124ull << 20));          // [124,125.4) g3red..p3
    float*          g3part  = (float*)(ws + (126ull << 20));          // [126,136) g3..g3red
    float*          cs_a    = (float*)(ws + (136ull << 20));          // [136,144) p1..p2
    float*          cs_h    = (float*)(ws + (144ull << 20));          // [144,152) p1..p3
    float*          hin     = cs_h;   // in-place

    dim3 blk(256);
    dim3 blk512(512);

    // operand prep
    cast_bf16<<<(MM * DMODEL / 4 + 255) / 256, blk, 0, stream>>>(x, x_bf, MM * DMODEL);
    transpose_cast<<<dim3((2 * DINNER) / 32, DMODEL / 32), dim3(32, 8), 0, stream>>>(
        W_in, Wint, DMODEL, 2 * DINNER);          // [1024][4096] -> [4096][1024]
    transpose_cast<<<dim3(DINNER / 32, DINNER / 32), dim3(32, 8), 0, stream>>>(
        pwk, pw_t, DINNER, DINNER);
    transpose_cast<<<dim3(DMODEL / 32, DINNER / 32), dim3(32, 8), 0, stream>>>(
        W_out, Woutt, DINNER, DMODEL);            // [2048][1024] -> [1024][2048]

    // G1: xz = x @ W_in, deinterleaved bf16 output (x_in | z)
    mfma_gemm<0, unsigned short><<<dim3((2 * DINNER) / 128, MM / 128, 1), blk512, 0, stream>>>(
        x_bf, Wint, x_in_bf, z_bf, DINNER, 0,
        MM, 2 * DINNER, DMODEL, DMODEL, DMODEL, DINNER, nullptr);

    // depthwise causal conv (bf16 in, bf16 out)
    dwconv_kernel<<<MM * DINNER / 4 / 256, blk, 0, stream>>>(x_in_bf, dwk, xcp_bf);

    // G2: xc = silu(conv @ pw + conv_bias) -> bf16
    mfma_gemm<1, unsigned short><<<dim3(DINNER / 128, MM / 128, 1), blk512, 0, stream>>>(
        xcp_bf, pw_t, xc_bf, xc_bf, DINNER + 1, 0,
        MM, DINNER, DINNER, DINNER, DINNER, DINNER, conv_bias);

    // G3: x_dbl = xc @ W_x  (split-K fp32, deterministic)
    g3_splitk<<<dim3(MM / 64, G3_KCH), blk, 0, stream>>>(xc_bf, W_x, g3part);
    g3_reduce<<<(MM * 80 / 4 + 255) / 256, blk, 0, stream>>>(g3part, xdbl);

    // G4: delta = softplus(x_dbl[:, :64] @ W_dt + b_dt)  (fp32)
    gemm_tiled_sp<<<dim3(DINNER / 64, MM / 64), blk, 0, stream>>>(
        xdbl, W_dt, delta, MM, DINNER, DTRANK, 80, DINNER, DINNER, b_dt);

    // selective scan, 3-pass chunked
    scan_pass1<<<dim3(DINNER / 256, NCH, Bb), blk, 0, stream>>>(
        delta, xc_bf, xdbl, A_log, cs_a, cs_h);
    scan_pass2<<<(Bb * 8 * DINNER + 255) / 256, blk, 0, stream>>>(cs_a, cs_h, hin);
    scan_pass3<<<dim3(DINNER / 256, NCH, Bb), blk, 0, stream>>>(
        delta, xc_bf, xdbl, A_log, hin, z_bf, Dv, y_bf);

    // G5: out = y @ W_out, split-K x2 (grid.z), fp32 partials + reduce
    mfma_gemm<0, float><<<dim3(DMODEL / 128, MM / 128, 2), blk512, 0, stream>>>(
        y_bf, Woutt, g5part, g5part, DMODEL + 1, (size_t)MM * DMODEL,
        MM, DMODEL, DINNER / 2, DINNER, DINNER, DMODEL, nullptr);
    g5_reduce<<<(MM * DMODEL / 4 + 255) / 256, blk, 0, stream>>>(
        g5part, out, MM * DMODEL);
}